// Round 6
// baseline (273.440 us; speedup 1.0000x reference)
//
#include <hip/hip_runtime.h>

#define B_ 2
#define S_ 2048
#define HID_ 1024
#define H_ 16
#define HKV_ 8
#define D_ 128

typedef unsigned short u16;
typedef __attribute__((ext_vector_type(8))) short short8;
typedef __attribute__((ext_vector_type(4))) float f32x4;
typedef __attribute__((ext_vector_type(16))) float f32x16;
typedef __attribute__((ext_vector_type(2))) unsigned short u16x2;
typedef __attribute__((ext_vector_type(4))) unsigned short u16x4;
typedef const __attribute__((address_space(1))) void gvoid;
typedef __attribute__((address_space(3))) void svoid;

__device__ __forceinline__ u16 f2b(float f) {
  union { float f; unsigned u; } v; v.f = f;
  unsigned r = v.u + 0x7FFFu + ((v.u >> 16) & 1u);
  return (u16)(r >> 16);
}
__device__ __forceinline__ float b2f(u16 x) {
  union { unsigned u; float f; } v; v.u = ((unsigned)x) << 16; return v.f;
}

__device__ __forceinline__ float exp2_fast(float x) {
  float r; asm("v_exp_f32 %0, %1" : "=v"(r) : "v"(x)); return r;
}
__device__ __forceinline__ unsigned cvtpk_bf16(float lo, float hi) {
  unsigned r; asm("v_cvt_pk_bf16_f32 %0, %1, %2" : "=v"(r) : "v"(lo), "v"(hi)); return r;
}
// explicit drain of async global_load_lds before a barrier (T3 recipe; m152 discipline)
__device__ __forceinline__ void vm_drain() {
  asm volatile("s_waitcnt vmcnt(0)" ::: "memory");
  __builtin_amdgcn_sched_barrier(0);
}

// ---------------- elementwise fp32 -> bf16 ----------------
__global__ __launch_bounds__(256) void conv_bf16_kernel(const float* __restrict__ X,
                                                        u16* __restrict__ Y, int n4) {
  int i = blockIdx.x * 256 + threadIdx.x;
  if (i < n4) {
    const float4 v = ((const float4*)X)[i];
    u16x4 o = { f2b(v.x), f2b(v.y), f2b(v.z), f2b(v.w) };
    ((u16x4*)Y)[i] = o;
  }
}

// ---------------- W [K,N] f32 -> Wt [N,K] bf16 (tiled transpose) ----------------
__global__ __launch_bounds__(256) void transpose_bf16_kernel(const float* __restrict__ W,
                                                             u16* __restrict__ Wt,
                                                             int K, int N) {
  __shared__ float t[32][33];
  const int nb = N >> 5;
  const int bx = blockIdx.x % nb;
  const int by = blockIdx.x / nb;
  const int tx = threadIdx.x & 31, ty = threadIdx.x >> 5;
#pragma unroll
  for (int i = 0; i < 32; i += 8)
    t[ty + i][tx] = W[(size_t)(by * 32 + ty + i) * N + bx * 32 + tx];
  __syncthreads();
#pragma unroll
  for (int i = 0; i < 32; i += 8)
    Wt[(size_t)(bx * 32 + ty + i) * K + by * 32 + tx] = f2b(t[tx][ty + i]);
}

// ---------------- RoPE cos/sin table ----------------
__global__ __launch_bounds__(256) void rope_table_kernel(const int* __restrict__ pid,
                                                         float* __restrict__ ct,
                                                         float* __restrict__ st) {
  int i = blockIdx.x * 256 + threadIdx.x;
  if (i >= S_ * 64) return;
  int s = i >> 6, f = i & 63;
  double inv = exp2(-(double)f * (19.931568569324174 / 64.0));
  double ang = (double)pid[s] * inv;
  ct[i] = (float)cos(ang);
  st[i] = (float)sin(ang);
}

// ---------------- GEMM: C[M,N] f32 = A[M,K]bf16 @ Bt[N,K]bf16^T ----------------
template <int M, int N, int K>
__global__ __launch_bounds__(256) void gemm_bt(const u16* __restrict__ A,
                                               const u16* __restrict__ Bt,
                                               float* __restrict__ C) {
  __shared__ u16 As[128 * 32];
  __shared__ u16 Bs[128 * 32];
  const int tid = threadIdx.x;
  const int w = tid >> 6;
  const int l = tid & 63;
  const int l15 = l & 15, lg = l >> 4;
  const int nbx = N / 128;
  const int bx = blockIdx.x % nbx, by = blockIdx.x / nbx;
  const int row0 = by * 128, col0 = bx * 128;
  const int wr = w >> 1, wc = w & 1;

  f32x4 acc[4][4];
#pragma unroll
  for (int m = 0; m < 4; ++m)
#pragma unroll
    for (int n = 0; n < 4; ++n) acc[m][n] = (f32x4){0.f, 0.f, 0.f, 0.f};

  for (int k0 = 0; k0 < K; k0 += 32) {
    __syncthreads();
#pragma unroll
    for (int i = 0; i < 2; ++i) {
      int c = i * 256 + tid;
      int r = c >> 2, cc = c & 3;
      const u16* sa = A + (size_t)(row0 + r) * K + k0 + cc * 8;
      __builtin_amdgcn_global_load_lds((gvoid*)sa, (svoid*)(As + (i * 256 + w * 64) * 8), 16, 0, 0);
      const u16* sb = Bt + (size_t)(col0 + r) * K + k0 + cc * 8;
      __builtin_amdgcn_global_load_lds((gvoid*)sb, (svoid*)(Bs + (i * 256 + w * 64) * 8), 16, 0, 0);
    }
    vm_drain();
    __syncthreads();
    short8 af[4], bf[4];
#pragma unroll
    for (int m = 0; m < 4; ++m)
      af[m] = *(const short8*)(As + (wr * 64 + m * 16 + l15) * 32 + lg * 8);
#pragma unroll
    for (int n = 0; n < 4; ++n)
      bf[n] = *(const short8*)(Bs + (wc * 64 + n * 16 + l15) * 32 + lg * 8);
#pragma unroll
    for (int m = 0; m < 4; ++m)
#pragma unroll
      for (int n = 0; n < 4; ++n)
        acc[m][n] = __builtin_amdgcn_mfma_f32_16x16x32_bf16(af[m], bf[n], acc[m][n], 0, 0, 0);
  }
#pragma unroll
  for (int m = 0; m < 4; ++m)
#pragma unroll
    for (int n = 0; n < 4; ++n) {
      float* cp = C + (size_t)(row0 + wr * 64 + m * 16 + lg * 4) * N + col0 + wc * 64 + n * 16 + l15;
#pragma unroll
      for (int r = 0; r < 4; ++r) cp[(size_t)r * N] = acc[m][n][r];
    }
}

// ---------------- RMSNorm + RoPE; writes bf16 [B,NH,S,D] (+ optional fp32) ----------------
template <int NH, bool WF>
__global__ __launch_bounds__(256) void norm_rope_kernel(const float* __restrict__ Xf,
                                                        const float* __restrict__ nw,
                                                        const float* __restrict__ ct,
                                                        const float* __restrict__ st,
                                                        u16* __restrict__ Ob,
                                                        float* __restrict__ Of) {
  const int w = threadIdx.x >> 6, l = threadIdx.x & 63;
  const int gid = blockIdx.x * 4 + w;
  const int head = gid % NH, row = gid / NH;
  const int b = row >> 11, s = row & 2047;
  const float* src = Xf + (size_t)row * (NH * 128) + head * 128 + l * 2;
  float x0 = src[0], x1 = src[1];
  float ssum = x0 * x0 + x1 * x1;
#pragma unroll
  for (int d = 1; d < 64; d <<= 1) ssum += __shfl_xor(ssum, d, 64);
  const float sc = rsqrtf(ssum * (1.0f / 128.0f) + 1e-6f);
  const float xn0 = x0 * sc * nw[l * 2];
  const float xn1 = x1 * sc * nw[l * 2 + 1];
  const float y0 = __shfl_xor(xn0, 32, 64);
  const float y1 = __shfl_xor(xn1, 32, 64);
  const int fi = (2 * l) & 63;
  const float c0 = ct[s * 64 + fi], c1 = ct[s * 64 + fi + 1];
  const float s0 = st[s * 64 + fi], s1 = st[s * 64 + fi + 1];
  const float sgn = (l < 32) ? -1.0f : 1.0f;
  const float o0 = xn0 * c0 + sgn * y0 * s0;
  const float o1 = xn1 * c1 + sgn * y1 * s1;
  size_t orow = ((size_t)(b * NH + head) * S_ + s) * 128 + l * 2;
  *(u16x2*)(Ob + orow) = (u16x2){f2b(o0), f2b(o1)};
  if (WF) { Of[orow] = o0; Of[orow + 1] = o1; }
}

// ---------------- V: [B,S,HKV,D] f32 -> vout [B,HKV,S,D] f32 + VT [B,HKV,D,S] bf16 ----------------
__global__ __launch_bounds__(256) void vtrans_kernel(const float* __restrict__ Vf,
                                                     float* __restrict__ vout,
                                                     u16* __restrict__ VTb) {
  __shared__ float t[32][33];
  const int bid = blockIdx.x;
  const int stile = bid & 63;
  const int dt = (bid >> 6) & 3;
  const int bh = bid >> 8;
  const int b = bh >> 3, hkv = bh & 7;
  const int tx = threadIdx.x & 31, ty = threadIdx.x >> 5;
#pragma unroll
  for (int j = 0; j < 4; ++j) {
    int s = stile * 32 + ty + 8 * j;
    t[ty + 8 * j][tx] = Vf[((size_t)(b * 2048 + s) * 8 + hkv) * 128 + dt * 32 + tx];
  }
  __syncthreads();
#pragma unroll
  for (int j = 0; j < 4; ++j) {
    int s = stile * 32 + ty + 8 * j;
    vout[((size_t)(b * 8 + hkv) * 2048 + s) * 128 + dt * 32 + tx] = t[ty + 8 * j][tx];
    int d = dt * 32 + ty + 8 * j;
    VTb[((size_t)(b * 8 + hkv) * 128 + d) * 2048 + stile * 32 + tx] = f2b(t[tx][ty + 8 * j]);
  }
}

// ---------------- flash attention (causal, GQA), 32x32 swapped-QK ----------------
// 512 blocks, EVERY block = exactly 17 kv-tiles (constant work, 2 blocks/CU).
// Pair p8: half0 = panel p8 (full, direct out) + first 15-2*p8 tiles of panel
// 15-p8 (partial 0); half1 = last 17 tiles of panel 15-p8 (partial 1).
// Split panels merged by attn_combine_kernel.
__global__ __launch_bounds__(256) void attn_kernel(const u16* __restrict__ Qb,
                                                   const u16* __restrict__ Kb,
                                                   const u16* __restrict__ VTb,
                                                   u16* __restrict__ Ab,
                                                   u16* __restrict__ Op,
                                                   float* __restrict__ Ml) {
  __shared__ u16 lds[2][16384];  // per buf: K tile [64][128] + VT tile [128][64]
  const int tid = threadIdx.x;
  const int w = tid >> 6, l = tid & 63;
  const int l31 = l & 31, hi = l >> 5;
  const int bid = blockIdx.x;
  const int half = bid & 1;
  const int pid = bid >> 1;           // 0..255
  const int b = pid >> 7;
  const int hh = (pid >> 3) & 15;
  const int p8 = pid & 7;
  const int hkv = hh >> 1;

  const u16* Kh = Kb + (size_t)(b * HKV_ + hkv) * S_ * 128;
  const u16* VTh = VTb + (size_t)(b * HKV_ + hkv) * 128 * S_;
  const float KSC = 0.12751740027f;  // (1/sqrt(128)) * log2(e)
  int cur = 0;

  auto stage = [&](int kt, int buf) {
    const u16* Kp = Kh + (size_t)kt * 64 * 128;
    const u16* Vp = VTh + kt * 64;
    u16* Kd = &lds[buf][0];
    u16* Vd = &lds[buf][8192];
#pragma unroll
    for (int i = 0; i < 4; ++i) {
      int c = i * 256 + tid;
      int kr = c >> 4, kc = c & 15;  // K: 64 rows x 16 chunks of 16B
      int kcs = kc ^ ((kr ^ (kr >> 3)) & 15);
      __builtin_amdgcn_global_load_lds((gvoid*)(Kp + kr * 128 + kcs * 8),
                                       (svoid*)(Kd + (i * 256 + w * 64) * 8), 16, 0, 0);
      int vd = c >> 3, vc = c & 7;   // VT: 128 rows x 8 chunks of 16B
      int vcs = vc ^ ((vd ^ (vd >> 3)) & 7);
      __builtin_amdgcn_global_load_lds((gvoid*)(Vp + (size_t)vd * S_ + vcs * 8),
                                       (svoid*)(Vd + (i * 256 + w * 64) * 8), 16, 0, 0);
    }
  };

  // mode: 0 = direct write to Ab, 1 = partial slot 0, 2 = partial slot 1
  auto run_seg = [&](int pp, int kt0, int kt1, int mode) {
    const int q0 = pp * 128;
    const int ntp = 2 * (pp + 1);       // panel's full tile count (for masking)
    const int qrow = q0 + w * 32 + l31;

    short8 qf[8];
    {
      const u16* qp = Qb + ((size_t)(b * H_ + hh) * S_ + qrow) * 128 + hi * 8;
#pragma unroll
      for (int c = 0; c < 8; ++c) qf[c] = *(const short8*)(qp + c * 16);
    }

    float m_run = -1e30f, l_run = 0.f;
    f32x16 oacc[4];
#pragma unroll
    for (int n = 0; n < 4; ++n)
#pragma unroll
      for (int r = 0; r < 16; ++r) oacc[n][r] = 0.f;

    stage(kt0, cur);
    vm_drain();
    __syncthreads();
    for (int kt = kt0; kt < kt1; ++kt) {
      if (kt + 1 < kt1) stage(kt + 1, cur ^ 1);
      const u16* Kl = &lds[cur][0];
      const u16* Vl = &lds[cur][8192];

      // ---- QK^T (swapped): rows=kv, col=q ----
      f32x16 st_[2];
#pragma unroll
      for (int t = 0; t < 2; ++t) {
#pragma unroll
        for (int r = 0; r < 16; ++r) st_[t][r] = 0.f;
        const int row = t * 32 + l31;
        const int rb = row * 256, sw = ((row ^ (row >> 3)) & 15) << 4;
#pragma unroll
        for (int c = 0; c < 8; ++c) {
          short8 kf = *(const short8*)((const char*)Kl + rb + ((c * 32 + hi * 16) ^ sw));
          st_[t] = __builtin_amdgcn_mfma_f32_32x32x16_bf16(kf, qf[c], st_[t], 0, 0, 0);
        }
      }

      // ---- softmax (lane-local, base-2 domain) ----
      float pv[2][16];
      float mx = -1e30f;
      const bool domask = (kt >= ntp - 2);
#pragma unroll
      for (int t = 0; t < 2; ++t)
#pragma unroll
        for (int r = 0; r < 16; ++r) {
          float x = st_[t][r] * KSC;
          if (domask) {
            int kv = kt * 64 + t * 32 + (r & 3) + 8 * (r >> 2) + 4 * hi;
            if (kv > qrow) x = -1e30f;
          }
          pv[t][r] = x;
          mx = fmaxf(mx, x);
        }
      mx = fmaxf(mx, __shfl_xor(mx, 32, 64));

      if (__any(mx > m_run + 8.0f)) {
        float mnew = fmaxf(m_run, mx);
        float corr = exp2_fast(m_run - mnew);
        l_run *= corr;
        m_run = mnew;
#pragma unroll
        for (int r = 0; r < 16; ++r) {
          float cr = __shfl(corr, (r & 3) + 8 * (r >> 2) + 4 * hi, 64);
#pragma unroll
          for (int n = 0; n < 4; ++n) oacc[n][r] *= cr;
        }
      }

      float ls = 0.f;
#pragma unroll
      for (int t = 0; t < 2; ++t)
#pragma unroll
        for (int r = 0; r < 16; ++r) {
          float p = exp2_fast(pv[t][r] - m_run);
          pv[t][r] = p;
          ls += p;
        }
      l_run += ls + __shfl_xor(ls, 32, 64);

      // ---- P -> bf16 A-fragments ----
      unsigned paw[4][4];
#pragma unroll
      for (int t = 0; t < 2; ++t) {
        unsigned W[4][2], Wx[4][2];
#pragma unroll
        for (int g = 0; g < 4; ++g)
#pragma unroll
          for (int i = 0; i < 2; ++i) {
            W[g][i] = cvtpk_bf16(pv[t][4 * g + 2 * i], pv[t][4 * g + 2 * i + 1]);
            Wx[g][i] = __shfl_xor(W[g][i], 32, 64);
          }
#pragma unroll
        for (int cc = 0; cc < 2; ++cc) {
          paw[t * 2 + cc][0] = hi ? Wx[2 * cc + 1][0] : W[2 * cc][0];
          paw[t * 2 + cc][1] = hi ? Wx[2 * cc + 1][1] : W[2 * cc][1];
          paw[t * 2 + cc][2] = hi ? W[2 * cc + 1][0] : Wx[2 * cc][0];
          paw[t * 2 + cc][3] = hi ? W[2 * cc + 1][1] : Wx[2 * cc][1];
        }
      }

      // ---- PV ----
#pragma unroll
      for (int cp = 0; cp < 4; ++cp) {
        short8 paf;
        ((unsigned*)&paf)[0] = paw[cp][0];
        ((unsigned*)&paf)[1] = paw[cp][1];
        ((unsigned*)&paf)[2] = paw[cp][2];
        ((unsigned*)&paf)[3] = paw[cp][3];
#pragma unroll
        for (int n = 0; n < 4; ++n) {
          const int d = n * 32 + l31;
          const int swv = ((d ^ (d >> 3)) & 7) << 4;
          short8 vf = *(const short8*)((const char*)Vl + d * 128 + ((cp * 32 + hi * 16) ^ swv));
          oacc[n] = __builtin_amdgcn_mfma_f32_32x32x16_bf16(paf, vf, oacc[n], 0, 0, 0);
        }
      }
      vm_drain();
      __syncthreads();
      cur ^= 1;
    }

    if (mode == 0) {
#pragma unroll
      for (int r = 0; r < 16; ++r) {
        const int ql = (r & 3) + 8 * (r >> 2) + 4 * hi;
        float lb = __shfl(l_run, ql, 64);
        float inv = 1.0f / lb;
        const int q = q0 + w * 32 + ql;
        u16* op = Ab + ((size_t)(b * S_) + q) * 2048 + hh * 128 + l31;
#pragma unroll
        for (int n = 0; n < 4; ++n) op[n * 32] = f2b(oacc[n][r] * inv);
      }
    } else {
      const int part = mode - 1;
      u16* ob = Op + ((size_t)(part * 256 + pid)) * 128 * 128;
#pragma unroll
      for (int r = 0; r < 16; ++r) {
        const int ql = (r & 3) + 8 * (r >> 2) + 4 * hi;
        const int qq = w * 32 + ql;
#pragma unroll
        for (int n = 0; n < 4; ++n) ob[qq * 128 + n * 32 + l31] = f2b(oacc[n][r]);
      }
      if (hi == 0) {
        float* mlb = Ml + ((size_t)(part * 256 + pid)) * 256;
        mlb[w * 32 + l31] = m_run;
        mlb[128 + w * 32 + l31] = l_run;
      }
    }
  };

  if (half == 0) {
    run_seg(p8, 0, 2 * p8 + 2, 0);
    run_seg(15 - p8, 0, 15 - 2 * p8, 1);
  } else {
    run_seg(15 - p8, 15 - 2 * p8, 32 - 2 * p8, 2);
  }
}

// ---------------- merge split panels: Ab = (w0*O0 + w1*O1) / (w0*l0 + w1*l1) ----------------
__global__ __launch_bounds__(256) void attn_combine_kernel(const u16* __restrict__ Op,
                                                           const float* __restrict__ Ml,
                                                           u16* __restrict__ Ab) {
  const int pid = blockIdx.x;  // 0..255
  const int b = pid >> 7, hh = (pid >> 3) & 15, p8 = pid & 7;
  const int pp = 15 - p8;
  const int q = threadIdx.x >> 1;
  const int d0 = (threadIdx.x & 1) * 64;
  const float* ml0 = Ml + (size_t)pid * 256;
  const float* ml1 = Ml + (size_t)(256 + pid) * 256;
  const float m0 = ml0[q], l0 = ml0[128 + q];
  const float m1 = ml1[q], l1 = ml1[128 + q];
  const float m = fmaxf(m0, m1);
  const float w0 = exp2_fast(m0 - m), w1 = exp2_fast(m1 - m);
  const float linv = 1.0f / (w0 * l0 + w1 * l1);
  const u16* o0 = Op + ((size_t)pid * 128 + q) * 128 + d0;
  const u16* o1 = Op + ((size_t)(256 + pid) * 128 + q) * 128 + d0;
  u16* ab = Ab + ((size_t)(b * S_) + pp * 128 + q) * 2048 + hh * 128 + d0;
#pragma unroll
  for (int c = 0; c < 8; ++c) {
    short8 a = *(const short8*)(o0 + c * 8);
    short8 bb = *(const short8*)(o1 + c * 8);
    short8 o;
#pragma unroll
    for (int j = 0; j < 8; ++j)
      o[j] = (short)f2b((w0 * b2f((u16)a[j]) + w1 * b2f((u16)bb[j])) * linv);
    *(short8*)(ab + c * 8) = o;
  }
}

extern "C" void kernel_launch(void* const* d_in, const int* in_sizes, int n_in,
                              void* d_out, int out_size, void* d_ws, size_t ws_size,
                              hipStream_t stream) {
  const float* hs  = (const float*)d_in[0];
  const int*   pid = (const int*)d_in[1];
  const float* Wq  = (const float*)d_in[2];
  const float* Wk  = (const float*)d_in[3];
  const float* Wv  = (const float*)d_in[4];
  const float* Wo  = (const float*)d_in[5];
  const float* qnw = (const float*)d_in[6];
  const float* knw = (const float*)d_in[7];

  float* out0 = (float*)d_out;
  float* kout = out0 + (size_t)B_ * HKV_ * S_ * D_;
  float* vout = kout + (size_t)B_ * HKV_ * S_ * D_;

  char* ws = (char*)d_ws;
  size_t off = 0;
  auto alloc = [&](size_t bytes) {
    void* p = ws + off;
    off += (bytes + 255) & ~(size_t)255;
    return p;
  };
  u16*   Xb  = (u16*)alloc((size_t)4096 * 1024 * 2);
  u16*   Wqt = (u16*)alloc((size_t)2048 * 1024 * 2);
  u16*   Wkt = (u16*)alloc((size_t)1024 * 1024 * 2);
  u16*   Wvt = (u16*)alloc((size_t)1024 * 1024 * 2);
  u16*   Wot = (u16*)alloc((size_t)1024 * 2048 * 2);
  float* ct  = (float*)alloc((size_t)2048 * 64 * 4);
  float* st  = (float*)alloc((size_t)2048 * 64 * 4);
  float* Qf  = (float*)alloc((size_t)4096 * 2048 * 4);
  float* Kf  = (float*)alloc((size_t)4096 * 1024 * 4);
  float* Vf  = (float*)alloc((size_t)4096 * 1024 * 4);
  u16*   Qbb = (u16*)alloc((size_t)B_ * H_ * S_ * D_ * 2);
  u16*   Kbb = (u16*)alloc((size_t)B_ * HKV_ * S_ * D_ * 2);
  u16*   VTb = (u16*)alloc((size_t)B_ * HKV_ * D_ * S_ * 2);
  u16*   Ab  = (u16*)Qf;   // alias: Qf dead after norm_rope; Ab 16MB <= 32MB
  u16*   Op  = (u16*)Kf;   // alias: Kf dead after norm_rope; Op 2*256*128*128*2 = 16.78MB = sizeof(Kf)
  float* Ml  = Vf;         // alias: Vf dead after vtrans; Ml 0.5MB

  conv_bf16_kernel<<<4096, 256, 0, stream>>>(hs, Xb, 4096 * 1024 / 4);
  transpose_bf16_kernel<<<(1024 / 32) * (2048 / 32), 256, 0, stream>>>(Wq, Wqt, 1024, 2048);
  transpose_bf16_kernel<<<(1024 / 32) * (1024 / 32), 256, 0, stream>>>(Wk, Wkt, 1024, 1024);
  transpose_bf16_kernel<<<(1024 / 32) * (1024 / 32), 256, 0, stream>>>(Wv, Wvt, 1024, 1024);
  transpose_bf16_kernel<<<(2048 / 32) * (1024 / 32), 256, 0, stream>>>(Wo, Wot, 2048, 1024);
  rope_table_kernel<<<512, 256, 0, stream>>>(pid, ct, st);

  gemm_bt<4096, 2048, 1024><<<32 * 16, 256, 0, stream>>>(Xb, Wqt, Qf);
  gemm_bt<4096, 1024, 1024><<<32 * 8, 256, 0, stream>>>(Xb, Wkt, Kf);
  gemm_bt<4096, 1024, 1024><<<32 * 8, 256, 0, stream>>>(Xb, Wvt, Vf);

  norm_rope_kernel<16, false><<<16384, 256, 0, stream>>>(Qf, qnw, ct, st, Qbb, nullptr);
  norm_rope_kernel<8, true><<<8192, 256, 0, stream>>>(Kf, knw, ct, st, Kbb, kout);
  vtrans_kernel<<<4096, 256, 0, stream>>>(Vf, vout, VTb);

  attn_kernel<<<512, 256, 0, stream>>>(Qbb, Kbb, VTb, Ab, Op, Ml);
  attn_combine_kernel<<<256, 256, 0, stream>>>(Op, Ml, Ab);

  gemm_bt<4096, 1024, 2048><<<32 * 8, 256, 0, stream>>>(Ab, Wot, out0);
}

// Round 7
// 243.953 us; speedup vs baseline: 1.1209x; 1.1209x over previous
//
#include <hip/hip_runtime.h>

#define B_ 2
#define S_ 2048
#define HID_ 1024
#define H_ 16
#define HKV_ 8
#define D_ 128

typedef unsigned short u16;
typedef __attribute__((ext_vector_type(8))) short short8;
typedef __attribute__((ext_vector_type(4))) float f32x4;
typedef __attribute__((ext_vector_type(16))) float f32x16;
typedef __attribute__((ext_vector_type(2))) unsigned short u16x2;
typedef __attribute__((ext_vector_type(4))) unsigned short u16x4;
typedef const __attribute__((address_space(1))) void gvoid;
typedef __attribute__((address_space(3))) void svoid;

__device__ __forceinline__ u16 f2b(float f) {
  union { float f; unsigned u; } v; v.f = f;
  unsigned r = v.u + 0x7FFFu + ((v.u >> 16) & 1u);
  return (u16)(r >> 16);
}
__device__ __forceinline__ float b2f(u16 x) {
  union { unsigned u; float f; } v; v.u = ((unsigned)x) << 16; return v.f;
}

__device__ __forceinline__ float exp2_fast(float x) {
  float r; asm("v_exp_f32 %0, %1" : "=v"(r) : "v"(x)); return r;
}
__device__ __forceinline__ unsigned cvtpk_bf16(float lo, float hi) {
  unsigned r; asm("v_cvt_pk_bf16_f32 %0, %1, %2" : "=v"(r) : "v"(lo), "v"(hi)); return r;
}
// explicit drain of async global_load_lds before a barrier (T3 recipe; m152 discipline)
__device__ __forceinline__ void vm_drain() {
  asm volatile("s_waitcnt vmcnt(0)" ::: "memory");
  __builtin_amdgcn_sched_barrier(0);
}

// ---------------- elementwise fp32 -> bf16 ----------------
__global__ __launch_bounds__(256) void conv_bf16_kernel(const float* __restrict__ X,
                                                        u16* __restrict__ Y, int n4) {
  int i = blockIdx.x * 256 + threadIdx.x;
  if (i < n4) {
    const float4 v = ((const float4*)X)[i];
    u16x4 o = { f2b(v.x), f2b(v.y), f2b(v.z), f2b(v.w) };
    ((u16x4*)Y)[i] = o;
  }
}

// ---------------- W [K,N] f32 -> Wt [N,K] bf16 (tiled transpose) ----------------
__global__ __launch_bounds__(256) void transpose_bf16_kernel(const float* __restrict__ W,
                                                             u16* __restrict__ Wt,
                                                             int K, int N) {
  __shared__ float t[32][33];
  const int nb = N >> 5;
  const int bx = blockIdx.x % nb;
  const int by = blockIdx.x / nb;
  const int tx = threadIdx.x & 31, ty = threadIdx.x >> 5;
#pragma unroll
  for (int i = 0; i < 32; i += 8)
    t[ty + i][tx] = W[(size_t)(by * 32 + ty + i) * N + bx * 32 + tx];
  __syncthreads();
#pragma unroll
  for (int i = 0; i < 32; i += 8)
    Wt[(size_t)(bx * 32 + ty + i) * K + by * 32 + tx] = f2b(t[tx][ty + i]);
}

// ---------------- RoPE cos/sin table ----------------
__global__ __launch_bounds__(256) void rope_table_kernel(const int* __restrict__ pid,
                                                         float* __restrict__ ct,
                                                         float* __restrict__ st) {
  int i = blockIdx.x * 256 + threadIdx.x;
  if (i >= S_ * 64) return;
  int s = i >> 6, f = i & 63;
  double inv = exp2(-(double)f * (19.931568569324174 / 64.0));
  double ang = (double)pid[s] * inv;
  ct[i] = (float)cos(ang);
  st[i] = (float)sin(ang);
}

// ---------------- GEMM: C[M,N] f32 = A[M,K]bf16 @ Bt[N,K]bf16^T ----------------
template <int M, int N, int K>
__global__ __launch_bounds__(256) void gemm_bt(const u16* __restrict__ A,
                                               const u16* __restrict__ Bt,
                                               float* __restrict__ C) {
  __shared__ u16 As[128 * 32];
  __shared__ u16 Bs[128 * 32];
  const int tid = threadIdx.x;
  const int w = tid >> 6;
  const int l = tid & 63;
  const int l15 = l & 15, lg = l >> 4;
  const int nbx = N / 128;
  const int bx = blockIdx.x % nbx, by = blockIdx.x / nbx;
  const int row0 = by * 128, col0 = bx * 128;
  const int wr = w >> 1, wc = w & 1;

  f32x4 acc[4][4];
#pragma unroll
  for (int m = 0; m < 4; ++m)
#pragma unroll
    for (int n = 0; n < 4; ++n) acc[m][n] = (f32x4){0.f, 0.f, 0.f, 0.f};

  for (int k0 = 0; k0 < K; k0 += 32) {
    __syncthreads();
#pragma unroll
    for (int i = 0; i < 2; ++i) {
      int c = i * 256 + tid;
      int r = c >> 2, cc = c & 3;
      const u16* sa = A + (size_t)(row0 + r) * K + k0 + cc * 8;
      __builtin_amdgcn_global_load_lds((gvoid*)sa, (svoid*)(As + (i * 256 + w * 64) * 8), 16, 0, 0);
      const u16* sb = Bt + (size_t)(col0 + r) * K + k0 + cc * 8;
      __builtin_amdgcn_global_load_lds((gvoid*)sb, (svoid*)(Bs + (i * 256 + w * 64) * 8), 16, 0, 0);
    }
    vm_drain();
    __syncthreads();
    short8 af[4], bf[4];
#pragma unroll
    for (int m = 0; m < 4; ++m)
      af[m] = *(const short8*)(As + (wr * 64 + m * 16 + l15) * 32 + lg * 8);
#pragma unroll
    for (int n = 0; n < 4; ++n)
      bf[n] = *(const short8*)(Bs + (wc * 64 + n * 16 + l15) * 32 + lg * 8);
#pragma unroll
    for (int m = 0; m < 4; ++m)
#pragma unroll
      for (int n = 0; n < 4; ++n)
        acc[m][n] = __builtin_amdgcn_mfma_f32_16x16x32_bf16(af[m], bf[n], acc[m][n], 0, 0, 0);
  }
#pragma unroll
  for (int m = 0; m < 4; ++m)
#pragma unroll
    for (int n = 0; n < 4; ++n) {
      float* cp = C + (size_t)(row0 + wr * 64 + m * 16 + lg * 4) * N + col0 + wc * 64 + n * 16 + l15;
#pragma unroll
      for (int r = 0; r < 4; ++r) cp[(size_t)r * N] = acc[m][n][r];
    }
}

// ---------------- RMSNorm + RoPE; writes bf16 [B,NH,S,D] (+ optional fp32) ----------------
template <int NH, bool WF>
__global__ __launch_bounds__(256) void norm_rope_kernel(const float* __restrict__ Xf,
                                                        const float* __restrict__ nw,
                                                        const float* __restrict__ ct,
                                                        const float* __restrict__ st,
                                                        u16* __restrict__ Ob,
                                                        float* __restrict__ Of) {
  const int w = threadIdx.x >> 6, l = threadIdx.x & 63;
  const int gid = blockIdx.x * 4 + w;
  const int head = gid % NH, row = gid / NH;
  const int b = row >> 11, s = row & 2047;
  const float* src = Xf + (size_t)row * (NH * 128) + head * 128 + l * 2;
  float x0 = src[0], x1 = src[1];
  float ssum = x0 * x0 + x1 * x1;
#pragma unroll
  for (int d = 1; d < 64; d <<= 1) ssum += __shfl_xor(ssum, d, 64);
  const float sc = rsqrtf(ssum * (1.0f / 128.0f) + 1e-6f);
  const float xn0 = x0 * sc * nw[l * 2];
  const float xn1 = x1 * sc * nw[l * 2 + 1];
  const float y0 = __shfl_xor(xn0, 32, 64);
  const float y1 = __shfl_xor(xn1, 32, 64);
  const int fi = (2 * l) & 63;
  const float c0 = ct[s * 64 + fi], c1 = ct[s * 64 + fi + 1];
  const float s0 = st[s * 64 + fi], s1 = st[s * 64 + fi + 1];
  const float sgn = (l < 32) ? -1.0f : 1.0f;
  const float o0 = xn0 * c0 + sgn * y0 * s0;
  const float o1 = xn1 * c1 + sgn * y1 * s1;
  size_t orow = ((size_t)(b * NH + head) * S_ + s) * 128 + l * 2;
  *(u16x2*)(Ob + orow) = (u16x2){f2b(o0), f2b(o1)};
  if (WF) { Of[orow] = o0; Of[orow + 1] = o1; }
}

// ---------------- V: [B,S,HKV,D] f32 -> vout [B,HKV,S,D] f32 + VT [B,HKV,D,S] bf16 ----------------
__global__ __launch_bounds__(256) void vtrans_kernel(const float* __restrict__ Vf,
                                                     float* __restrict__ vout,
                                                     u16* __restrict__ VTb) {
  __shared__ float t[32][33];
  const int bid = blockIdx.x;
  const int stile = bid & 63;
  const int dt = (bid >> 6) & 3;
  const int bh = bid >> 8;
  const int b = bh >> 3, hkv = bh & 7;
  const int tx = threadIdx.x & 31, ty = threadIdx.x >> 5;
#pragma unroll
  for (int j = 0; j < 4; ++j) {
    int s = stile * 32 + ty + 8 * j;
    t[ty + 8 * j][tx] = Vf[((size_t)(b * 2048 + s) * 8 + hkv) * 128 + dt * 32 + tx];
  }
  __syncthreads();
#pragma unroll
  for (int j = 0; j < 4; ++j) {
    int s = stile * 32 + ty + 8 * j;
    vout[((size_t)(b * 8 + hkv) * 2048 + s) * 128 + dt * 32 + tx] = t[ty + 8 * j][tx];
    int d = dt * 32 + ty + 8 * j;
    VTb[((size_t)(b * 8 + hkv) * 128 + d) * 2048 + stile * 32 + tx] = f2b(t[tx][ty + 8 * j]);
  }
}

// ---------------- flash attention (causal, GQA), 32x32 swapped-QK ----------------
// 512 blocks, EVERY block = exactly 17 kv-tiles; __launch_bounds__(256,2) caps
// regs at 256/wave (unified VGPR+AGPR) so 2 blocks/CU actually co-reside.
// 64-kv tile processed as two 32-kv sub-tiles to cut live registers (~40).
__global__ __launch_bounds__(256, 2) void attn_kernel(const u16* __restrict__ Qb,
                                                      const u16* __restrict__ Kb,
                                                      const u16* __restrict__ VTb,
                                                      u16* __restrict__ Ab,
                                                      u16* __restrict__ Op,
                                                      float* __restrict__ Ml) {
  __shared__ u16 lds[2][16384];  // per buf: K tile [64][128] + VT tile [128][64]
  const int tid = threadIdx.x;
  const int w = tid >> 6, l = tid & 63;
  const int l31 = l & 31, hi = l >> 5;
  const int bid = blockIdx.x;
  const int half = bid & 1;
  const int pid = bid >> 1;           // 0..255
  const int b = pid >> 7;
  const int hh = (pid >> 3) & 15;
  const int p8 = pid & 7;
  const int hkv = hh >> 1;

  const u16* Kh = Kb + (size_t)(b * HKV_ + hkv) * S_ * 128;
  const u16* VTh = VTb + (size_t)(b * HKV_ + hkv) * 128 * S_;
  const float KSC = 0.12751740027f;  // (1/sqrt(128)) * log2(e)
  int cur = 0;

  auto stage = [&](int kt, int buf) {
    const u16* Kp = Kh + (size_t)kt * 64 * 128;
    const u16* Vp = VTh + kt * 64;
    u16* Kd = &lds[buf][0];
    u16* Vd = &lds[buf][8192];
#pragma unroll
    for (int i = 0; i < 4; ++i) {
      int c = i * 256 + tid;
      int kr = c >> 4, kc = c & 15;  // K: 64 rows x 16 chunks of 16B
      int kcs = kc ^ ((kr ^ (kr >> 3)) & 15);
      __builtin_amdgcn_global_load_lds((gvoid*)(Kp + kr * 128 + kcs * 8),
                                       (svoid*)(Kd + (i * 256 + w * 64) * 8), 16, 0, 0);
      int vd = c >> 3, vc = c & 7;   // VT: 128 rows x 8 chunks of 16B
      int vcs = vc ^ ((vd ^ (vd >> 3)) & 7);
      __builtin_amdgcn_global_load_lds((gvoid*)(Vp + (size_t)vd * S_ + vcs * 8),
                                       (svoid*)(Vd + (i * 256 + w * 64) * 8), 16, 0, 0);
    }
  };

  // mode: 0 = direct write to Ab, 1 = partial slot 0, 2 = partial slot 1
  auto run_seg = [&](int pp, int kt0, int kt1, int mode) {
    const int q0 = pp * 128;
    const int ntp = 2 * (pp + 1);       // panel's full tile count (for masking)
    const int qrow = q0 + w * 32 + l31;

    short8 qf[8];
    {
      const u16* qp = Qb + ((size_t)(b * H_ + hh) * S_ + qrow) * 128 + hi * 8;
#pragma unroll
      for (int c = 0; c < 8; ++c) qf[c] = *(const short8*)(qp + c * 16);
    }

    float m_run = -1e30f, l_run = 0.f;
    f32x16 oacc[4];
#pragma unroll
    for (int n = 0; n < 4; ++n)
#pragma unroll
      for (int r = 0; r < 16; ++r) oacc[n][r] = 0.f;

    stage(kt0, cur);
    vm_drain();
    __syncthreads();
    for (int kt = kt0; kt < kt1; ++kt) {
      if (kt + 1 < kt1) stage(kt + 1, cur ^ 1);
      const u16* Kl = &lds[cur][0];
      const u16* Vl = &lds[cur][8192];
      const bool domask = (kt >= ntp - 2);

      // process tile as two 32-kv sub-tiles (register trim: st/pv/paw halved)
#pragma unroll
      for (int ts = 0; ts < 2; ++ts) {
        // ---- QK^T (swapped): rows = kv subtile, col = q ----
        f32x16 stv;
#pragma unroll
        for (int r = 0; r < 16; ++r) stv[r] = 0.f;
        {
          const int row = ts * 32 + l31;
          const int rb = row * 256, sw = ((row ^ (row >> 3)) & 15) << 4;
#pragma unroll
          for (int c = 0; c < 8; ++c) {
            short8 kf = *(const short8*)((const char*)Kl + rb + ((c * 32 + hi * 16) ^ sw));
            stv = __builtin_amdgcn_mfma_f32_32x32x16_bf16(kf, qf[c], stv, 0, 0, 0);
          }
        }

        // ---- softmax (lane-local, base-2 domain) ----
        float pvv[16];
        float mx = -1e30f;
#pragma unroll
        for (int r = 0; r < 16; ++r) {
          float x = stv[r] * KSC;
          if (domask) {
            int kv = kt * 64 + ts * 32 + (r & 3) + 8 * (r >> 2) + 4 * hi;
            if (kv > qrow) x = -1e30f;
          }
          pvv[r] = x;
          mx = fmaxf(mx, x);
        }
        mx = fmaxf(mx, __shfl_xor(mx, 32, 64));

        if (__any(mx > m_run + 8.0f)) {
          float mnew = fmaxf(m_run, mx);
          float corr = exp2_fast(m_run - mnew);
          l_run *= corr;
          m_run = mnew;
#pragma unroll
          for (int r = 0; r < 16; ++r) {
            float cr = __shfl(corr, (r & 3) + 8 * (r >> 2) + 4 * hi, 64);
#pragma unroll
            for (int n = 0; n < 4; ++n) oacc[n][r] *= cr;
          }
        }

        float ls = 0.f;
#pragma unroll
        for (int r = 0; r < 16; ++r) {
          float p = exp2_fast(pvv[r] - m_run);
          pvv[r] = p;
          ls += p;
        }
        l_run += ls + __shfl_xor(ls, 32, 64);

        // ---- P -> bf16 A-fragments (cvt_pk + shfl_xor(32) + hi-select) ----
        unsigned W[4][2], Wx[4][2];
#pragma unroll
        for (int g = 0; g < 4; ++g)
#pragma unroll
          for (int i = 0; i < 2; ++i) {
            W[g][i] = cvtpk_bf16(pvv[4 * g + 2 * i], pvv[4 * g + 2 * i + 1]);
            Wx[g][i] = __shfl_xor(W[g][i], 32, 64);
          }

        // ---- PV: oacc[n] += P(32q x 16kv) x VT(32d x 16kv)^T, cp = ts*2+cc ----
#pragma unroll
        for (int cc = 0; cc < 2; ++cc) {
          short8 paf;
          ((unsigned*)&paf)[0] = hi ? Wx[2 * cc + 1][0] : W[2 * cc][0];
          ((unsigned*)&paf)[1] = hi ? Wx[2 * cc + 1][1] : W[2 * cc][1];
          ((unsigned*)&paf)[2] = hi ? W[2 * cc + 1][0] : Wx[2 * cc][0];
          ((unsigned*)&paf)[3] = hi ? W[2 * cc + 1][1] : Wx[2 * cc][1];
          const int cp = ts * 2 + cc;
#pragma unroll
          for (int n = 0; n < 4; ++n) {
            const int d = n * 32 + l31;
            const int swv = ((d ^ (d >> 3)) & 7) << 4;
            short8 vf = *(const short8*)((const char*)Vl + d * 128 + ((cp * 32 + hi * 16) ^ swv));
            oacc[n] = __builtin_amdgcn_mfma_f32_32x32x16_bf16(paf, vf, oacc[n], 0, 0, 0);
          }
        }
      }
      vm_drain();
      __syncthreads();
      cur ^= 1;
    }

    if (mode == 0) {
#pragma unroll
      for (int r = 0; r < 16; ++r) {
        const int ql = (r & 3) + 8 * (r >> 2) + 4 * hi;
        float lb = __shfl(l_run, ql, 64);
        float inv = 1.0f / lb;
        const int q = q0 + w * 32 + ql;
        u16* op = Ab + ((size_t)(b * S_) + q) * 2048 + hh * 128 + l31;
#pragma unroll
        for (int n = 0; n < 4; ++n) op[n * 32] = f2b(oacc[n][r] * inv);
      }
    } else {
      const int part = mode - 1;
      u16* ob = Op + ((size_t)(part * 256 + pid)) * 128 * 128;
#pragma unroll
      for (int r = 0; r < 16; ++r) {
        const int ql = (r & 3) + 8 * (r >> 2) + 4 * hi;
        const int qq = w * 32 + ql;
#pragma unroll
        for (int n = 0; n < 4; ++n) ob[qq * 128 + n * 32 + l31] = f2b(oacc[n][r]);
      }
      if (hi == 0) {
        float* mlb = Ml + ((size_t)(part * 256 + pid)) * 256;
        mlb[w * 32 + l31] = m_run;
        mlb[128 + w * 32 + l31] = l_run;
      }
    }
  };

  if (half == 0) {
    run_seg(p8, 0, 2 * p8 + 2, 0);
    run_seg(15 - p8, 0, 15 - 2 * p8, 1);
  } else {
    run_seg(15 - p8, 15 - 2 * p8, 32 - 2 * p8, 2);
  }
}

// ---------------- merge split panels: Ab = (w0*O0 + w1*O1) / (w0*l0 + w1*l1) ----------------
__global__ __launch_bounds__(256) void attn_combine_kernel(const u16* __restrict__ Op,
                                                           const float* __restrict__ Ml,
                                                           u16* __restrict__ Ab) {
  const int pid = blockIdx.x;  // 0..255
  const int b = pid >> 7, hh = (pid >> 3) & 15, p8 = pid & 7;
  const int pp = 15 - p8;
  const int q = threadIdx.x >> 1;
  const int d0 = (threadIdx.x & 1) * 64;
  const float* ml0 = Ml + (size_t)pid * 256;
  const float* ml1 = Ml + (size_t)(256 + pid) * 256;
  const float m0 = ml0[q], l0 = ml0[128 + q];
  const float m1 = ml1[q], l1 = ml1[128 + q];
  const float m = fmaxf(m0, m1);
  const float w0 = exp2_fast(m0 - m), w1 = exp2_fast(m1 - m);
  const float linv = 1.0f / (w0 * l0 + w1 * l1);
  const u16* o0 = Op + ((size_t)pid * 128 + q) * 128 + d0;
  const u16* o1 = Op + ((size_t)(256 + pid) * 128 + q) * 128 + d0;
  u16* ab = Ab + ((size_t)(b * S_) + pp * 128 + q) * 2048 + hh * 128 + d0;
#pragma unroll
  for (int c = 0; c < 8; ++c) {
    short8 a = *(const short8*)(o0 + c * 8);
    short8 bb = *(const short8*)(o1 + c * 8);
    short8 o;
#pragma unroll
    for (int j = 0; j < 8; ++j)
      o[j] = (short)f2b((w0 * b2f((u16)a[j]) + w1 * b2f((u16)bb[j])) * linv);
    *(short8*)(ab + c * 8) = o;
  }
}

extern "C" void kernel_launch(void* const* d_in, const int* in_sizes, int n_in,
                              void* d_out, int out_size, void* d_ws, size_t ws_size,
                              hipStream_t stream) {
  const float* hs  = (const float*)d_in[0];
  const int*   pid = (const int*)d_in[1];
  const float* Wq  = (const float*)d_in[2];
  const float* Wk  = (const float*)d_in[3];
  const float* Wv  = (const float*)d_in[4];
  const float* Wo  = (const float*)d_in[5];
  const float* qnw = (const float*)d_in[6];
  const float* knw = (const float*)d_in[7];

  float* out0 = (float*)d_out;
  float* kout = out0 + (size_t)B_ * HKV_ * S_ * D_;
  float* vout = kout + (size_t)B_ * HKV_ * S_ * D_;

  char* ws = (char*)d_ws;
  size_t off = 0;
  auto alloc = [&](size_t bytes) {
    void* p = ws + off;
    off += (bytes + 255) & ~(size_t)255;
    return p;
  };
  u16*   Xb  = (u16*)alloc((size_t)4096 * 1024 * 2);
  u16*   Wqt = (u16*)alloc((size_t)2048 * 1024 * 2);
  u16*   Wkt = (u16*)alloc((size_t)1024 * 1024 * 2);
  u16*   Wvt = (u16*)alloc((size_t)1024 * 1024 * 2);
  u16*   Wot = (u16*)alloc((size_t)1024 * 2048 * 2);
  float* ct  = (float*)alloc((size_t)2048 * 64 * 4);
  float* st  = (float*)alloc((size_t)2048 * 64 * 4);
  float* Qf  = (float*)alloc((size_t)4096 * 2048 * 4);
  float* Kf  = (float*)alloc((size_t)4096 * 1024 * 4);
  float* Vf  = (float*)alloc((size_t)4096 * 1024 * 4);
  u16*   Qbb = (u16*)alloc((size_t)B_ * H_ * S_ * D_ * 2);
  u16*   Kbb = (u16*)alloc((size_t)B_ * HKV_ * S_ * D_ * 2);
  u16*   VTb = (u16*)alloc((size_t)B_ * HKV_ * D_ * S_ * 2);
  u16*   Ab  = (u16*)Qf;   // alias: Qf dead after norm_rope; Ab 16MB <= 32MB
  u16*   Op  = (u16*)Kf;   // alias: Kf dead after norm_rope; Op 16.78MB = sizeof(Kf)
  float* Ml  = Vf;         // alias: Vf dead after vtrans; Ml 0.5MB

  conv_bf16_kernel<<<4096, 256, 0, stream>>>(hs, Xb, 4096 * 1024 / 4);
  transpose_bf16_kernel<<<(1024 / 32) * (2048 / 32), 256, 0, stream>>>(Wq, Wqt, 1024, 2048);
  transpose_bf16_kernel<<<(1024 / 32) * (1024 / 32), 256, 0, stream>>>(Wk, Wkt, 1024, 1024);
  transpose_bf16_kernel<<<(1024 / 32) * (1024 / 32), 256, 0, stream>>>(Wv, Wvt, 1024, 1024);
  transpose_bf16_kernel<<<(2048 / 32) * (1024 / 32), 256, 0, stream>>>(Wo, Wot, 2048, 1024);
  rope_table_kernel<<<512, 256, 0, stream>>>(pid, ct, st);

  gemm_bt<4096, 2048, 1024><<<32 * 16, 256, 0, stream>>>(Xb, Wqt, Qf);
  gemm_bt<4096, 1024, 1024><<<32 * 8, 256, 0, stream>>>(Xb, Wkt, Kf);
  gemm_bt<4096, 1024, 1024><<<32 * 8, 256, 0, stream>>>(Xb, Wvt, Vf);

  norm_rope_kernel<16, false><<<16384, 256, 0, stream>>>(Qf, qnw, ct, st, Qbb, nullptr);
  norm_rope_kernel<8, true><<<8192, 256, 0, stream>>>(Kf, knw, ct, st, Kbb, kout);
  vtrans_kernel<<<4096, 256, 0, stream>>>(Vf, vout, VTb);

  attn_kernel<<<512, 256, 0, stream>>>(Qbb, Kbb, VTb, Ab, Op, Ml);
  attn_combine_kernel<<<256, 256, 0, stream>>>(Op, Ml, Ab);

  gemm_bt<4096, 1024, 2048><<<32 * 8, 256, 0, stream>>>(Ab, Wot, out0);
}

// Round 8
// 209.734 us; speedup vs baseline: 1.3037x; 1.1632x over previous
//
#include <hip/hip_runtime.h>

#define B_ 2
#define S_ 2048
#define HID_ 1024
#define H_ 16
#define HKV_ 8
#define D_ 128

typedef unsigned short u16;
typedef __attribute__((ext_vector_type(8))) short short8;
typedef __attribute__((ext_vector_type(4))) float f32x4;
typedef __attribute__((ext_vector_type(16))) float f32x16;
typedef __attribute__((ext_vector_type(2))) unsigned short u16x2;
typedef __attribute__((ext_vector_type(4))) unsigned short u16x4;
typedef const __attribute__((address_space(1))) void gvoid;
typedef __attribute__((address_space(3))) void svoid;

__device__ __forceinline__ u16 f2b(float f) {
  union { float f; unsigned u; } v; v.f = f;
  unsigned r = v.u + 0x7FFFu + ((v.u >> 16) & 1u);
  return (u16)(r >> 16);
}
__device__ __forceinline__ float b2f(u16 x) {
  union { unsigned u; float f; } v; v.u = ((unsigned)x) << 16; return v.f;
}

__device__ __forceinline__ float exp2_fast(float x) {
  float r; asm("v_exp_f32 %0, %1" : "=v"(r) : "v"(x)); return r;
}
__device__ __forceinline__ unsigned cvtpk_bf16(float lo, float hi) {
  unsigned r; asm("v_cvt_pk_bf16_f32 %0, %1, %2" : "=v"(r) : "v"(lo), "v"(hi)); return r;
}
// explicit drain of async global_load_lds before a barrier (T3 recipe; m152 discipline)
__device__ __forceinline__ void vm_drain() {
  asm volatile("s_waitcnt vmcnt(0)" ::: "memory");
  __builtin_amdgcn_sched_barrier(0);
}

// ---------------- elementwise fp32 -> bf16 ----------------
__global__ __launch_bounds__(256) void conv_bf16_kernel(const float* __restrict__ X,
                                                        u16* __restrict__ Y, int n4) {
  int i = blockIdx.x * 256 + threadIdx.x;
  if (i < n4) {
    const float4 v = ((const float4*)X)[i];
    u16x4 o = { f2b(v.x), f2b(v.y), f2b(v.z), f2b(v.w) };
    ((u16x4*)Y)[i] = o;
  }
}

// ---------------- W [K,N] f32 -> Wt [N,K] bf16 (tiled transpose) ----------------
__global__ __launch_bounds__(256) void transpose_bf16_kernel(const float* __restrict__ W,
                                                             u16* __restrict__ Wt,
                                                             int K, int N) {
  __shared__ float t[32][33];
  const int nb = N >> 5;
  const int bx = blockIdx.x % nb;
  const int by = blockIdx.x / nb;
  const int tx = threadIdx.x & 31, ty = threadIdx.x >> 5;
#pragma unroll
  for (int i = 0; i < 32; i += 8)
    t[ty + i][tx] = W[(size_t)(by * 32 + ty + i) * N + bx * 32 + tx];
  __syncthreads();
#pragma unroll
  for (int i = 0; i < 32; i += 8)
    Wt[(size_t)(bx * 32 + ty + i) * K + by * 32 + tx] = f2b(t[tx][ty + i]);
}

// ---------------- RoPE cos/sin table ----------------
__global__ __launch_bounds__(256) void rope_table_kernel(const int* __restrict__ pid,
                                                         float* __restrict__ ct,
                                                         float* __restrict__ st) {
  int i = blockIdx.x * 256 + threadIdx.x;
  if (i >= S_ * 64) return;
  int s = i >> 6, f = i & 63;
  double inv = exp2(-(double)f * (19.931568569324174 / 64.0));
  double ang = (double)pid[s] * inv;
  ct[i] = (float)cos(ang);
  st[i] = (float)sin(ang);
}

// ---------------- GEMM: C[M,N] f32 = A[M,K]bf16 @ Bt[N,K]bf16^T ----------------
// BM = 128 (wave: 64x64, acc[4][4]) or 64 (wave: 32x64, acc[2][4]).
template <int M, int N, int K, int BM>
__global__ __launch_bounds__(256) void gemm_bt(const u16* __restrict__ A,
                                               const u16* __restrict__ Bt,
                                               float* __restrict__ C) {
  __shared__ u16 As[BM * 32];
  __shared__ u16 Bs[128 * 32];
  const int tid = threadIdx.x;
  const int w = tid >> 6;
  const int l = tid & 63;
  const int l15 = l & 15, lg = l >> 4;
  const int nbx = N / 128;
  const int bx = blockIdx.x % nbx, by = blockIdx.x / nbx;
  const int row0 = by * BM, col0 = bx * 128;
  const int wr = w >> 1, wc = w & 1;
  constexpr int MR = BM / 32;  // m-fragments per wave

  f32x4 acc[MR][4];
#pragma unroll
  for (int m = 0; m < MR; ++m)
#pragma unroll
    for (int n = 0; n < 4; ++n) acc[m][n] = (f32x4){0.f, 0.f, 0.f, 0.f};

  for (int k0 = 0; k0 < K; k0 += 32) {
    __syncthreads();
#pragma unroll
    for (int i = 0; i < BM / 64; ++i) {
      int c = i * 256 + tid;
      int r = c >> 2, cc = c & 3;
      const u16* sa = A + (size_t)(row0 + r) * K + k0 + cc * 8;
      __builtin_amdgcn_global_load_lds((gvoid*)sa, (svoid*)(As + (i * 256 + w * 64) * 8), 16, 0, 0);
    }
#pragma unroll
    for (int i = 0; i < 2; ++i) {
      int c = i * 256 + tid;
      int r = c >> 2, cc = c & 3;
      const u16* sb = Bt + (size_t)(col0 + r) * K + k0 + cc * 8;
      __builtin_amdgcn_global_load_lds((gvoid*)sb, (svoid*)(Bs + (i * 256 + w * 64) * 8), 16, 0, 0);
    }
    vm_drain();
    __syncthreads();
    short8 af[MR], bf[4];
#pragma unroll
    for (int m = 0; m < MR; ++m)
      af[m] = *(const short8*)(As + (wr * (BM / 2) + m * 16 + l15) * 32 + lg * 8);
#pragma unroll
    for (int n = 0; n < 4; ++n)
      bf[n] = *(const short8*)(Bs + (wc * 64 + n * 16 + l15) * 32 + lg * 8);
#pragma unroll
    for (int m = 0; m < MR; ++m)
#pragma unroll
      for (int n = 0; n < 4; ++n)
        acc[m][n] = __builtin_amdgcn_mfma_f32_16x16x32_bf16(af[m], bf[n], acc[m][n], 0, 0, 0);
  }
#pragma unroll
  for (int m = 0; m < MR; ++m)
#pragma unroll
    for (int n = 0; n < 4; ++n) {
      float* cp = C + (size_t)(row0 + wr * (BM / 2) + m * 16 + lg * 4) * N + col0 + wc * 64 + n * 16 + l15;
#pragma unroll
      for (int r = 0; r < 4; ++r) cp[(size_t)r * N] = acc[m][n][r];
    }
}

// ---------------- RMSNorm + RoPE; reads fused [.,STRIDE] f32; writes bf16 [B,NH,S,D] (+ optional fp32) ----------------
template <int NH, bool WF, int STRIDE>
__global__ __launch_bounds__(256) void norm_rope_kernel(const float* __restrict__ Xf,
                                                        const float* __restrict__ nw,
                                                        const float* __restrict__ ct,
                                                        const float* __restrict__ st,
                                                        u16* __restrict__ Ob,
                                                        float* __restrict__ Of) {
  const int w = threadIdx.x >> 6, l = threadIdx.x & 63;
  const int gid = blockIdx.x * 4 + w;
  const int head = gid % NH, row = gid / NH;
  const int b = row >> 11, s = row & 2047;
  const float* src = Xf + (size_t)row * STRIDE + head * 128 + l * 2;
  float x0 = src[0], x1 = src[1];
  float ssum = x0 * x0 + x1 * x1;
#pragma unroll
  for (int d = 1; d < 64; d <<= 1) ssum += __shfl_xor(ssum, d, 64);
  const float sc = rsqrtf(ssum * (1.0f / 128.0f) + 1e-6f);
  const float xn0 = x0 * sc * nw[l * 2];
  const float xn1 = x1 * sc * nw[l * 2 + 1];
  const float y0 = __shfl_xor(xn0, 32, 64);
  const float y1 = __shfl_xor(xn1, 32, 64);
  const int fi = (2 * l) & 63;
  const float c0 = ct[s * 64 + fi], c1 = ct[s * 64 + fi + 1];
  const float s0 = st[s * 64 + fi], s1 = st[s * 64 + fi + 1];
  const float sgn = (l < 32) ? -1.0f : 1.0f;
  const float o0 = xn0 * c0 + sgn * y0 * s0;
  const float o1 = xn1 * c1 + sgn * y1 * s1;
  size_t orow = ((size_t)(b * NH + head) * S_ + s) * 128 + l * 2;
  *(u16x2*)(Ob + orow) = (u16x2){f2b(o0), f2b(o1)};
  if (WF) { Of[orow] = o0; Of[orow + 1] = o1; }
}

// ---------------- V: fused [.,4096] f32 -> vout [B,HKV,S,D] f32 + VT [B,HKV,D,S] bf16 ----------------
__global__ __launch_bounds__(256) void vtrans_kernel(const float* __restrict__ Vf,
                                                     float* __restrict__ vout,
                                                     u16* __restrict__ VTb) {
  __shared__ float t[32][33];
  const int bid = blockIdx.x;
  const int stile = bid & 63;
  const int dt = (bid >> 6) & 3;
  const int bh = bid >> 8;
  const int b = bh >> 3, hkv = bh & 7;
  const int tx = threadIdx.x & 31, ty = threadIdx.x >> 5;
#pragma unroll
  for (int j = 0; j < 4; ++j) {
    int s = stile * 32 + ty + 8 * j;
    t[ty + 8 * j][tx] = Vf[(size_t)(b * 2048 + s) * 4096 + hkv * 128 + dt * 32 + tx];
  }
  __syncthreads();
#pragma unroll
  for (int j = 0; j < 4; ++j) {
    int s = stile * 32 + ty + 8 * j;
    vout[((size_t)(b * 8 + hkv) * 2048 + s) * 128 + dt * 32 + tx] = t[ty + 8 * j][tx];
    int d = dt * 32 + ty + 8 * j;
    VTb[((size_t)(b * 8 + hkv) * 128 + d) * 2048 + stile * 32 + tx] = f2b(t[tx][ty + 8 * j]);
  }
}

// ---------------- flash attention (causal, GQA), 32x32 swapped-QK ----------------
// 512 blocks, EVERY block = exactly 17 kv-tiles; __launch_bounds__(256,2) caps
// regs at 256/wave (unified VGPR+AGPR) so 2 blocks/CU actually co-reside.
// 64-kv tile processed as two 32-kv sub-tiles to cut live registers (~40).
__global__ __launch_bounds__(256, 2) void attn_kernel(const u16* __restrict__ Qb,
                                                      const u16* __restrict__ Kb,
                                                      const u16* __restrict__ VTb,
                                                      u16* __restrict__ Ab,
                                                      u16* __restrict__ Op,
                                                      float* __restrict__ Ml) {
  __shared__ u16 lds[2][16384];  // per buf: K tile [64][128] + VT tile [128][64]
  const int tid = threadIdx.x;
  const int w = tid >> 6, l = tid & 63;
  const int l31 = l & 31, hi = l >> 5;
  const int bid = blockIdx.x;
  const int half = bid & 1;
  const int pid = bid >> 1;           // 0..255
  const int b = pid >> 7;
  const int hh = (pid >> 3) & 15;
  const int p8 = pid & 7;
  const int hkv = hh >> 1;

  const u16* Kh = Kb + (size_t)(b * HKV_ + hkv) * S_ * 128;
  const u16* VTh = VTb + (size_t)(b * HKV_ + hkv) * 128 * S_;
  const float KSC = 0.12751740027f;  // (1/sqrt(128)) * log2(e)
  int cur = 0;

  auto stage = [&](int kt, int buf) {
    const u16* Kp = Kh + (size_t)kt * 64 * 128;
    const u16* Vp = VTh + kt * 64;
    u16* Kd = &lds[buf][0];
    u16* Vd = &lds[buf][8192];
#pragma unroll
    for (int i = 0; i < 4; ++i) {
      int c = i * 256 + tid;
      int kr = c >> 4, kc = c & 15;  // K: 64 rows x 16 chunks of 16B
      int kcs = kc ^ ((kr ^ (kr >> 3)) & 15);
      __builtin_amdgcn_global_load_lds((gvoid*)(Kp + kr * 128 + kcs * 8),
                                       (svoid*)(Kd + (i * 256 + w * 64) * 8), 16, 0, 0);
      int vd = c >> 3, vc = c & 7;   // VT: 128 rows x 8 chunks of 16B
      int vcs = vc ^ ((vd ^ (vd >> 3)) & 7);
      __builtin_amdgcn_global_load_lds((gvoid*)(Vp + (size_t)vd * S_ + vcs * 8),
                                       (svoid*)(Vd + (i * 256 + w * 64) * 8), 16, 0, 0);
    }
  };

  // mode: 0 = direct write to Ab, 1 = partial slot 0, 2 = partial slot 1
  auto run_seg = [&](int pp, int kt0, int kt1, int mode) {
    const int q0 = pp * 128;
    const int ntp = 2 * (pp + 1);       // panel's full tile count (for masking)
    const int qrow = q0 + w * 32 + l31;

    short8 qf[8];
    {
      const u16* qp = Qb + ((size_t)(b * H_ + hh) * S_ + qrow) * 128 + hi * 8;
#pragma unroll
      for (int c = 0; c < 8; ++c) qf[c] = *(const short8*)(qp + c * 16);
    }

    float m_run = -1e30f, l_run = 0.f;
    f32x16 oacc[4];
#pragma unroll
    for (int n = 0; n < 4; ++n)
#pragma unroll
      for (int r = 0; r < 16; ++r) oacc[n][r] = 0.f;

    stage(kt0, cur);
    vm_drain();
    __syncthreads();
    for (int kt = kt0; kt < kt1; ++kt) {
      if (kt + 1 < kt1) stage(kt + 1, cur ^ 1);
      const u16* Kl = &lds[cur][0];
      const u16* Vl = &lds[cur][8192];
      const bool domask = (kt >= ntp - 2);

      // process tile as two 32-kv sub-tiles (register trim: st/pv/paw halved)
#pragma unroll
      for (int ts = 0; ts < 2; ++ts) {
        // ---- QK^T (swapped): rows = kv subtile, col = q ----
        f32x16 stv;
#pragma unroll
        for (int r = 0; r < 16; ++r) stv[r] = 0.f;
        {
          const int row = ts * 32 + l31;
          const int rb = row * 256, sw = ((row ^ (row >> 3)) & 15) << 4;
#pragma unroll
          for (int c = 0; c < 8; ++c) {
            short8 kf = *(const short8*)((const char*)Kl + rb + ((c * 32 + hi * 16) ^ sw));
            stv = __builtin_amdgcn_mfma_f32_32x32x16_bf16(kf, qf[c], stv, 0, 0, 0);
          }
        }

        // ---- softmax (lane-local, base-2 domain) ----
        float pvv[16];
        float mx = -1e30f;
#pragma unroll
        for (int r = 0; r < 16; ++r) {
          float x = stv[r] * KSC;
          if (domask) {
            int kv = kt * 64 + ts * 32 + (r & 3) + 8 * (r >> 2) + 4 * hi;
            if (kv > qrow) x = -1e30f;
          }
          pvv[r] = x;
          mx = fmaxf(mx, x);
        }
        mx = fmaxf(mx, __shfl_xor(mx, 32, 64));

        if (__any(mx > m_run + 8.0f)) {
          float mnew = fmaxf(m_run, mx);
          float corr = exp2_fast(m_run - mnew);
          l_run *= corr;
          m_run = mnew;
#pragma unroll
          for (int r = 0; r < 16; ++r) {
            float cr = __shfl(corr, (r & 3) + 8 * (r >> 2) + 4 * hi, 64);
#pragma unroll
            for (int n = 0; n < 4; ++n) oacc[n][r] *= cr;
          }
        }

        float ls = 0.f;
#pragma unroll
        for (int r = 0; r < 16; ++r) {
          float p = exp2_fast(pvv[r] - m_run);
          pvv[r] = p;
          ls += p;
        }
        l_run += ls + __shfl_xor(ls, 32, 64);

        // ---- P -> bf16 A-fragments (cvt_pk + shfl_xor(32) + hi-select) ----
        unsigned W[4][2], Wx[4][2];
#pragma unroll
        for (int g = 0; g < 4; ++g)
#pragma unroll
          for (int i = 0; i < 2; ++i) {
            W[g][i] = cvtpk_bf16(pvv[4 * g + 2 * i], pvv[4 * g + 2 * i + 1]);
            Wx[g][i] = __shfl_xor(W[g][i], 32, 64);
          }

        // ---- PV: oacc[n] += P(32q x 16kv) x VT(32d x 16kv)^T, cp = ts*2+cc ----
#pragma unroll
        for (int cc = 0; cc < 2; ++cc) {
          short8 paf;
          ((unsigned*)&paf)[0] = hi ? Wx[2 * cc + 1][0] : W[2 * cc][0];
          ((unsigned*)&paf)[1] = hi ? Wx[2 * cc + 1][1] : W[2 * cc][1];
          ((unsigned*)&paf)[2] = hi ? W[2 * cc + 1][0] : Wx[2 * cc][0];
          ((unsigned*)&paf)[3] = hi ? W[2 * cc + 1][1] : Wx[2 * cc][1];
          const int cp = ts * 2 + cc;
#pragma unroll
          for (int n = 0; n < 4; ++n) {
            const int d = n * 32 + l31;
            const int swv = ((d ^ (d >> 3)) & 7) << 4;
            short8 vf = *(const short8*)((const char*)Vl + d * 128 + ((cp * 32 + hi * 16) ^ swv));
            oacc[n] = __builtin_amdgcn_mfma_f32_32x32x16_bf16(paf, vf, oacc[n], 0, 0, 0);
          }
        }
      }
      vm_drain();
      __syncthreads();
      cur ^= 1;
    }

    if (mode == 0) {
#pragma unroll
      for (int r = 0; r < 16; ++r) {
        const int ql = (r & 3) + 8 * (r >> 2) + 4 * hi;
        float lb = __shfl(l_run, ql, 64);
        float inv = 1.0f / lb;
        const int q = q0 + w * 32 + ql;
        u16* op = Ab + ((size_t)(b * S_) + q) * 2048 + hh * 128 + l31;
#pragma unroll
        for (int n = 0; n < 4; ++n) op[n * 32] = f2b(oacc[n][r] * inv);
      }
    } else {
      const int part = mode - 1;
      u16* ob = Op + ((size_t)(part * 256 + pid)) * 128 * 128;
#pragma unroll
      for (int r = 0; r < 16; ++r) {
        const int ql = (r & 3) + 8 * (r >> 2) + 4 * hi;
        const int qq = w * 32 + ql;
#pragma unroll
        for (int n = 0; n < 4; ++n) ob[qq * 128 + n * 32 + l31] = f2b(oacc[n][r]);
      }
      if (hi == 0) {
        float* mlb = Ml + ((size_t)(part * 256 + pid)) * 256;
        mlb[w * 32 + l31] = m_run;
        mlb[128 + w * 32 + l31] = l_run;
      }
    }
  };

  if (half == 0) {
    run_seg(p8, 0, 2 * p8 + 2, 0);
    run_seg(15 - p8, 0, 15 - 2 * p8, 1);
  } else {
    run_seg(15 - p8, 15 - 2 * p8, 32 - 2 * p8, 2);
  }
}

// ---------------- merge split panels: Ab = (w0*O0 + w1*O1) / (w0*l0 + w1*l1) ----------------
__global__ __launch_bounds__(256) void attn_combine_kernel(const u16* __restrict__ Op,
                                                           const float* __restrict__ Ml,
                                                           u16* __restrict__ Ab) {
  const int pid = blockIdx.x;  // 0..255
  const int b = pid >> 7, hh = (pid >> 3) & 15, p8 = pid & 7;
  const int pp = 15 - p8;
  const int q = threadIdx.x >> 1;
  const int d0 = (threadIdx.x & 1) * 64;
  const float* ml0 = Ml + (size_t)pid * 256;
  const float* ml1 = Ml + (size_t)(256 + pid) * 256;
  const float m0 = ml0[q], l0 = ml0[128 + q];
  const float m1 = ml1[q], l1 = ml1[128 + q];
  const float m = fmaxf(m0, m1);
  const float w0 = exp2_fast(m0 - m), w1 = exp2_fast(m1 - m);
  const float linv = 1.0f / (w0 * l0 + w1 * l1);
  const u16* o0 = Op + ((size_t)pid * 128 + q) * 128 + d0;
  const u16* o1 = Op + ((size_t)(256 + pid) * 128 + q) * 128 + d0;
  u16* ab = Ab + ((size_t)(b * S_) + pp * 128 + q) * 2048 + hh * 128 + d0;
#pragma unroll
  for (int c = 0; c < 8; ++c) {
    short8 a = *(const short8*)(o0 + c * 8);
    short8 bb = *(const short8*)(o1 + c * 8);
    short8 o;
#pragma unroll
    for (int j = 0; j < 8; ++j)
      o[j] = (short)f2b((w0 * b2f((u16)a[j]) + w1 * b2f((u16)bb[j])) * linv);
    *(short8*)(ab + c * 8) = o;
  }
}

extern "C" void kernel_launch(void* const* d_in, const int* in_sizes, int n_in,
                              void* d_out, int out_size, void* d_ws, size_t ws_size,
                              hipStream_t stream) {
  const float* hs  = (const float*)d_in[0];
  const int*   pid = (const int*)d_in[1];
  const float* Wq  = (const float*)d_in[2];
  const float* Wk  = (const float*)d_in[3];
  const float* Wv  = (const float*)d_in[4];
  const float* Wo  = (const float*)d_in[5];
  const float* qnw = (const float*)d_in[6];
  const float* knw = (const float*)d_in[7];

  float* out0 = (float*)d_out;
  float* kout = out0 + (size_t)B_ * HKV_ * S_ * D_;
  float* vout = kout + (size_t)B_ * HKV_ * S_ * D_;

  char* ws = (char*)d_ws;
  size_t off = 0;
  auto alloc = [&](size_t bytes) {
    void* p = ws + off;
    off += (bytes + 255) & ~(size_t)255;
    return p;
  };
  u16*   Xb    = (u16*)alloc((size_t)4096 * 1024 * 2);
  u16*   Wqkvt = (u16*)alloc((size_t)4096 * 1024 * 2);  // rows: Q 0..2047, K 2048..3071, V 3072..4095
  u16*   Wot   = (u16*)alloc((size_t)1024 * 2048 * 2);
  float* ct    = (float*)alloc((size_t)2048 * 64 * 4);
  float* st    = (float*)alloc((size_t)2048 * 64 * 4);
  float* QKVf  = (float*)alloc((size_t)4096 * 4096 * 4); // fused projection out, 64MB
  u16*   Qbb   = (u16*)alloc((size_t)B_ * H_ * S_ * D_ * 2);
  u16*   Kbb   = (u16*)alloc((size_t)B_ * HKV_ * S_ * D_ * 2);
  u16*   VTb   = (u16*)alloc((size_t)B_ * HKV_ * D_ * S_ * 2);
  // aliases into QKVf (dead after norm_rope/vtrans consume it):
  u16*   Ab = (u16*)QKVf;                                   // 16MB
  u16*   Op = (u16*)QKVf + (size_t)8192 * 1024;             // 16.78MB at +16MB
  float* Ml = (float*)((char*)QKVf + (size_t)34 * 1024 * 1024);  // 0.5MB at +34MB

  conv_bf16_kernel<<<4096, 256, 0, stream>>>(hs, Xb, 4096 * 1024 / 4);
  transpose_bf16_kernel<<<(2048 / 32) * (1024 / 32), 256, 0, stream>>>(Wq, Wqkvt, 1024, 2048);
  transpose_bf16_kernel<<<(1024 / 32) * (1024 / 32), 256, 0, stream>>>(Wk, Wqkvt + (size_t)2048 * 1024, 1024, 1024);
  transpose_bf16_kernel<<<(1024 / 32) * (1024 / 32), 256, 0, stream>>>(Wv, Wqkvt + (size_t)3072 * 1024, 1024, 1024);
  transpose_bf16_kernel<<<(1024 / 32) * (2048 / 32), 256, 0, stream>>>(Wo, Wot, 2048, 1024);
  rope_table_kernel<<<512, 256, 0, stream>>>(pid, ct, st);

  // fused QKV projection: [4096,1024] @ [1024,4096] -> [4096,4096], 1024 blocks (4/CU)
  gemm_bt<4096, 4096, 1024, 128><<<32 * 32, 256, 0, stream>>>(Xb, Wqkvt, QKVf);

  norm_rope_kernel<16, false, 4096><<<16384, 256, 0, stream>>>(QKVf, qnw, ct, st, Qbb, nullptr);
  norm_rope_kernel<8, true, 4096><<<8192, 256, 0, stream>>>(QKVf + 2048, knw, ct, st, Kbb, kout);
  vtrans_kernel<<<4096, 256, 0, stream>>>(QKVf + 3072, vout, VTb);

  attn_kernel<<<512, 256, 0, stream>>>(Qbb, Kbb, VTb, Ab, Op, Ml);
  attn_combine_kernel<<<256, 256, 0, stream>>>(Op, Ml, Ab);

  // O projection: BM=64 tiles -> 512 blocks (2/CU)
  gemm_bt<4096, 1024, 2048, 64><<<8 * 64, 256, 0, stream>>>(Ab, Wot, out0);
}

// Round 9
// 181.964 us; speedup vs baseline: 1.5027x; 1.1526x over previous
//
#include <hip/hip_runtime.h>

#define B_ 2
#define S_ 2048
#define HID_ 1024
#define H_ 16
#define HKV_ 8
#define D_ 128

typedef unsigned short u16;
typedef __attribute__((ext_vector_type(8))) short short8;
typedef __attribute__((ext_vector_type(4))) float f32x4;
typedef __attribute__((ext_vector_type(16))) float f32x16;
typedef __attribute__((ext_vector_type(2))) unsigned short u16x2;
typedef __attribute__((ext_vector_type(4))) unsigned short u16x4;
typedef const __attribute__((address_space(1))) void gvoid;
typedef __attribute__((address_space(3))) void svoid;

__device__ __forceinline__ u16 f2b(float f) {
  union { float f; unsigned u; } v; v.f = f;
  unsigned r = v.u + 0x7FFFu + ((v.u >> 16) & 1u);
  return (u16)(r >> 16);
}
__device__ __forceinline__ float b2f(u16 x) {
  union { unsigned u; float f; } v; v.u = ((unsigned)x) << 16; return v.f;
}

__device__ __forceinline__ float exp2_fast(float x) {
  float r; asm("v_exp_f32 %0, %1" : "=v"(r) : "v"(x)); return r;
}
__device__ __forceinline__ unsigned cvtpk_bf16(float lo, float hi) {
  unsigned r; asm("v_cvt_pk_bf16_f32 %0, %1, %2" : "=v"(r) : "v"(lo), "v"(hi)); return r;
}
// explicit drain of async global_load_lds before a barrier (T3 recipe; m152 discipline)
__device__ __forceinline__ void vm_drain() {
  asm volatile("s_waitcnt vmcnt(0)" ::: "memory");
  __builtin_amdgcn_sched_barrier(0);
}

// ---------------- elementwise fp32 -> bf16 ----------------
__global__ __launch_bounds__(256) void conv_bf16_kernel(const float* __restrict__ X,
                                                        u16* __restrict__ Y, int n4) {
  int i = blockIdx.x * 256 + threadIdx.x;
  if (i < n4) {
    const float4 v = ((const float4*)X)[i];
    u16x4 o = { f2b(v.x), f2b(v.y), f2b(v.z), f2b(v.w) };
    ((u16x4*)Y)[i] = o;
  }
}

// ---------------- W [K,N] f32 -> Wt [N',K] bf16 (tiled transpose) ----------------
// PERM: within each 128-col head, permute d -> p so RoPE pairs (d,d+64) land in
// adjacent MFMA n-fragments of the same lane in the fused GEMM epilogue.
// p(d) = (d&15) | ((d>>6&1)<<4) | ((d>>4&1)<<5) | ((d>>5&1)<<6)
template <bool PERM>
__global__ __launch_bounds__(256) void transpose_bf16_kernel(const float* __restrict__ W,
                                                             u16* __restrict__ Wt,
                                                             int K, int N) {
  __shared__ float t[32][33];
  const int nb = N >> 5;
  const int bx = blockIdx.x % nb;
  const int by = blockIdx.x / nb;
  const int tx = threadIdx.x & 31, ty = threadIdx.x >> 5;
#pragma unroll
  for (int i = 0; i < 32; i += 8)
    t[ty + i][tx] = W[(size_t)(by * 32 + ty + i) * N + bx * 32 + tx];
  __syncthreads();
#pragma unroll
  for (int i = 0; i < 32; i += 8) {
    int n = bx * 32 + ty + i;
    int nn;
    if (PERM) {
      int head = n >> 7, d = n & 127;
      int p = (d & 15) | (((d >> 6) & 1) << 4) | (((d >> 4) & 1) << 5) | (((d >> 5) & 1) << 6);
      nn = head * 128 + p;
    } else {
      nn = n;
    }
    Wt[(size_t)nn * K + by * 32 + tx] = f2b(t[tx][ty + i]);
  }
}

// ---------------- RoPE cos/sin table, transposed [64][2048] ----------------
__global__ __launch_bounds__(256) void rope_table_kernel(const int* __restrict__ pid,
                                                         float* __restrict__ ct,
                                                         float* __restrict__ st) {
  int i = blockIdx.x * 256 + threadIdx.x;  // f = i>>11, s = i&2047
  if (i >= 64 * S_) return;
  int f = i >> 11, s = i & 2047;
  double inv = exp2(-(double)f * (19.931568569324174 / 64.0));  // 1e6^(-f/64)
  double ang = (double)pid[s] * inv;
  ct[i] = (float)cos(ang);
  st[i] = (float)sin(ang);
}

// ---------------- plain GEMM (O-projection): C = A @ Bt^T ----------------
template <int M, int N, int K, int BM>
__global__ __launch_bounds__(256) void gemm_bt(const u16* __restrict__ A,
                                               const u16* __restrict__ Bt,
                                               float* __restrict__ C) {
  __shared__ u16 As[BM * 32];
  __shared__ u16 Bs[128 * 32];
  const int tid = threadIdx.x;
  const int w = tid >> 6;
  const int l = tid & 63;
  const int l15 = l & 15, lg = l >> 4;
  const int nbx = N / 128;
  const int bx = blockIdx.x % nbx, by = blockIdx.x / nbx;
  const int row0 = by * BM, col0 = bx * 128;
  const int wr = w >> 1, wc = w & 1;
  constexpr int MR = BM / 32;

  f32x4 acc[MR][4];
#pragma unroll
  for (int m = 0; m < MR; ++m)
#pragma unroll
    for (int n = 0; n < 4; ++n) acc[m][n] = (f32x4){0.f, 0.f, 0.f, 0.f};

  for (int k0 = 0; k0 < K; k0 += 32) {
    __syncthreads();
#pragma unroll
    for (int i = 0; i < BM / 64; ++i) {
      int c = i * 256 + tid;
      int r = c >> 2, cc = c & 3;
      const u16* sa = A + (size_t)(row0 + r) * K + k0 + cc * 8;
      __builtin_amdgcn_global_load_lds((gvoid*)sa, (svoid*)(As + (i * 256 + w * 64) * 8), 16, 0, 0);
    }
#pragma unroll
    for (int i = 0; i < 2; ++i) {
      int c = i * 256 + tid;
      int r = c >> 2, cc = c & 3;
      const u16* sb = Bt + (size_t)(col0 + r) * K + k0 + cc * 8;
      __builtin_amdgcn_global_load_lds((gvoid*)sb, (svoid*)(Bs + (i * 256 + w * 64) * 8), 16, 0, 0);
    }
    vm_drain();
    __syncthreads();
    short8 af[MR], bf[4];
#pragma unroll
    for (int m = 0; m < MR; ++m)
      af[m] = *(const short8*)(As + (wr * (BM / 2) + m * 16 + l15) * 32 + lg * 8);
#pragma unroll
    for (int n = 0; n < 4; ++n)
      bf[n] = *(const short8*)(Bs + (wc * 64 + n * 16 + l15) * 32 + lg * 8);
#pragma unroll
    for (int m = 0; m < MR; ++m)
#pragma unroll
      for (int n = 0; n < 4; ++n)
        acc[m][n] = __builtin_amdgcn_mfma_f32_16x16x32_bf16(af[m], bf[n], acc[m][n], 0, 0, 0);
  }
#pragma unroll
  for (int m = 0; m < MR; ++m)
#pragma unroll
    for (int n = 0; n < 4; ++n) {
      float* cp = C + (size_t)(row0 + wr * (BM / 2) + m * 16 + lg * 4) * N + col0 + wc * 64 + n * 16 + l15;
#pragma unroll
      for (int r = 0; r < 4; ++r) cp[(size_t)r * N] = acc[m][n][r];
    }
}

// ---------------- fused QKV GEMM + RMSNorm + RoPE + layout epilogue ----------------
// C block (by,bx): rows 128 s-values, cols = one head's 128 dims.
// bx<16: Q head bx (permuted cols) -> Qbb bf16 [B,16,S,128]
// 16<=bx<24: K head bx-16 (permuted) -> Kbb bf16 + kout f32 [B,8,S,128]
// bx>=24: V head bx-24 (plain cols) -> vout f32 [B,8,S,128] + VTb bf16 [B,8,128,S]
__global__ __launch_bounds__(256) void gemm_qkv_fused(const u16* __restrict__ A,
                                                      const u16* __restrict__ Bt,
                                                      const float* __restrict__ qnw,
                                                      const float* __restrict__ knw,
                                                      const float* __restrict__ ct_t,
                                                      const float* __restrict__ st_t,
                                                      u16* __restrict__ Qbb,
                                                      u16* __restrict__ Kbb,
                                                      float* __restrict__ kout,
                                                      float* __restrict__ vout,
                                                      u16* __restrict__ VTb) {
  constexpr int K = 1024;
  __shared__ u16 As[128 * 32];
  __shared__ u16 Bs[128 * 32];
  __shared__ float red[128][2];
  const int tid = threadIdx.x;
  const int w = tid >> 6;
  const int l = tid & 63;
  const int l15 = l & 15, lg = l >> 4;
  const int bx = blockIdx.x & 31, by = blockIdx.x >> 5;
  const int row0 = by * 128, col0 = bx * 128;
  const int wr = w >> 1, wc = w & 1;

  f32x4 acc[4][4];
#pragma unroll
  for (int m = 0; m < 4; ++m)
#pragma unroll
    for (int n = 0; n < 4; ++n) acc[m][n] = (f32x4){0.f, 0.f, 0.f, 0.f};

  for (int k0 = 0; k0 < K; k0 += 32) {
    __syncthreads();
#pragma unroll
    for (int i = 0; i < 2; ++i) {
      int c = i * 256 + tid;
      int r = c >> 2, cc = c & 3;
      const u16* sa = A + (size_t)(row0 + r) * K + k0 + cc * 8;
      __builtin_amdgcn_global_load_lds((gvoid*)sa, (svoid*)(As + (i * 256 + w * 64) * 8), 16, 0, 0);
      const u16* sb = Bt + (size_t)(col0 + r) * K + k0 + cc * 8;
      __builtin_amdgcn_global_load_lds((gvoid*)sb, (svoid*)(Bs + (i * 256 + w * 64) * 8), 16, 0, 0);
    }
    vm_drain();
    __syncthreads();
    short8 af[4], bf[4];
#pragma unroll
    for (int m = 0; m < 4; ++m)
      af[m] = *(const short8*)(As + (wr * 64 + m * 16 + l15) * 32 + lg * 8);
#pragma unroll
    for (int n = 0; n < 4; ++n)
      bf[n] = *(const short8*)(Bs + (wc * 64 + n * 16 + l15) * 32 + lg * 8);
#pragma unroll
    for (int m = 0; m < 4; ++m)
#pragma unroll
      for (int n = 0; n < 4; ++n)
        acc[m][n] = __builtin_amdgcn_mfma_f32_16x16x32_bf16(af[m], bf[n], acc[m][n], 0, 0, 0);
  }

  // ---- fused epilogue ----
  const int b_ = row0 >> 11;
  const int s0 = row0 & 2047;
  if (bx < 24) {
    // RMSNorm row-sums over the block's 128 cols (= the head's full dim)
    float part[4][4];
#pragma unroll
    for (int m = 0; m < 4; ++m)
#pragma unroll
      for (int r = 0; r < 4; ++r) {
        float p = 0.f;
#pragma unroll
        for (int n = 0; n < 4; ++n) p += acc[m][n][r] * acc[m][n][r];
        part[m][r] = p;
      }
#pragma unroll
    for (int i = 1; i < 16; i <<= 1)
#pragma unroll
      for (int m = 0; m < 4; ++m)
#pragma unroll
        for (int r = 0; r < 4; ++r) part[m][r] += __shfl_xor(part[m][r], i, 64);
    if (l15 == 0) {
#pragma unroll
      for (int m = 0; m < 4; ++m)
#pragma unroll
        for (int r = 0; r < 4; ++r) red[wr * 64 + m * 16 + lg * 4 + r][wc] = part[m][r];
    }
    __syncthreads();

    const bool isQ = bx < 16;
    const int h = isQ ? bx : bx - 16;
    const float* nw = isQ ? qnw : knw;
    u16* outb = isQ ? Qbb : Kbb;
    const int NH = isQ ? 16 : 8;
#pragma unroll
    for (int np = 0; np < 2; ++np) {
      const int d_lo = l15 + 32 * wc + 16 * np;  // permuted-col -> physical d (pair d_lo,d_lo+64)
      const float w_lo = nw[d_lo], w_hi = nw[d_lo + 64];
#pragma unroll
      for (int m = 0; m < 4; ++m) {
        const int sb = s0 + wr * 64 + m * 16 + lg * 4;
        const float4 cv = *(const float4*)(ct_t + d_lo * 2048 + sb);
        const float4 sv = *(const float4*)(st_t + d_lo * 2048 + sb);
#pragma unroll
        for (int r = 0; r < 4; ++r) {
          const int ro = wr * 64 + m * 16 + lg * 4 + r;
          const float tot = red[ro][0] + red[ro][1];
          const float rms = rsqrtf(tot * (1.0f / 128.0f) + 1e-6f);
          const float xl = acc[m][2 * np][r] * rms * w_lo;
          const float xh = acc[m][2 * np + 1][r] * rms * w_hi;
          const float cc = ((const float*)&cv)[r], ss = ((const float*)&sv)[r];
          const float ol = xl * cc - xh * ss;
          const float oh = xh * cc + xl * ss;
          const size_t base = ((size_t)(b_ * NH + h) * 2048 + sb + r) * 128;
          outb[base + d_lo] = f2b(ol);
          outb[base + d_lo + 64] = f2b(oh);
          if (!isQ) {
            kout[base + d_lo] = ol;
            kout[base + d_lo + 64] = oh;
          }
        }
      }
    }
  } else {
    const int h = bx - 24;
#pragma unroll
    for (int n = 0; n < 4; ++n) {
      const int d = wc * 64 + n * 16 + l15;  // V cols unpermuted
#pragma unroll
      for (int m = 0; m < 4; ++m) {
        const int sb = s0 + wr * 64 + m * 16 + lg * 4;
        u16x4 pk;
#pragma unroll
        for (int r = 0; r < 4; ++r) {
          const float x = acc[m][n][r];
          vout[((size_t)(b_ * 8 + h) * 2048 + sb + r) * 128 + d] = x;
          pk[r] = f2b(x);
        }
        *(u16x4*)(VTb + ((size_t)(b_ * 8 + h) * 128 + d) * 2048 + sb) = pk;
      }
    }
  }
}

// ---------------- flash attention (causal, GQA), 32x32 swapped-QK ----------------
// 512 blocks, EVERY block = exactly 17 kv-tiles; __launch_bounds__(256,2) caps
// regs at 256/wave (unified VGPR+AGPR) so 2 blocks/CU actually co-reside.
__global__ __launch_bounds__(256, 2) void attn_kernel(const u16* __restrict__ Qb,
                                                      const u16* __restrict__ Kb,
                                                      const u16* __restrict__ VTb,
                                                      u16* __restrict__ Ab,
                                                      u16* __restrict__ Op,
                                                      float* __restrict__ Ml) {
  __shared__ u16 lds[2][16384];  // per buf: K tile [64][128] + VT tile [128][64]
  const int tid = threadIdx.x;
  const int w = tid >> 6, l = tid & 63;
  const int l31 = l & 31, hi = l >> 5;
  const int bid = blockIdx.x;
  const int half = bid & 1;
  const int pid = bid >> 1;           // 0..255
  const int b = pid >> 7;
  const int hh = (pid >> 3) & 15;
  const int p8 = pid & 7;
  const int hkv = hh >> 1;

  const u16* Kh = Kb + (size_t)(b * HKV_ + hkv) * S_ * 128;
  const u16* VTh = VTb + (size_t)(b * HKV_ + hkv) * 128 * S_;
  const float KSC = 0.12751740027f;  // (1/sqrt(128)) * log2(e)
  int cur = 0;

  auto stage = [&](int kt, int buf) {
    const u16* Kp = Kh + (size_t)kt * 64 * 128;
    const u16* Vp = VTh + kt * 64;
    u16* Kd = &lds[buf][0];
    u16* Vd = &lds[buf][8192];
#pragma unroll
    for (int i = 0; i < 4; ++i) {
      int c = i * 256 + tid;
      int kr = c >> 4, kc = c & 15;
      int kcs = kc ^ ((kr ^ (kr >> 3)) & 15);
      __builtin_amdgcn_global_load_lds((gvoid*)(Kp + kr * 128 + kcs * 8),
                                       (svoid*)(Kd + (i * 256 + w * 64) * 8), 16, 0, 0);
      int vd = c >> 3, vc = c & 7;
      int vcs = vc ^ ((vd ^ (vd >> 3)) & 7);
      __builtin_amdgcn_global_load_lds((gvoid*)(Vp + (size_t)vd * S_ + vcs * 8),
                                       (svoid*)(Vd + (i * 256 + w * 64) * 8), 16, 0, 0);
    }
  };

  auto run_seg = [&](int pp, int kt0, int kt1, int mode) {
    const int q0 = pp * 128;
    const int ntp = 2 * (pp + 1);
    const int qrow = q0 + w * 32 + l31;

    short8 qf[8];
    {
      const u16* qp = Qb + ((size_t)(b * H_ + hh) * S_ + qrow) * 128 + hi * 8;
#pragma unroll
      for (int c = 0; c < 8; ++c) qf[c] = *(const short8*)(qp + c * 16);
    }

    float m_run = -1e30f, l_run = 0.f;
    f32x16 oacc[4];
#pragma unroll
    for (int n = 0; n < 4; ++n)
#pragma unroll
      for (int r = 0; r < 16; ++r) oacc[n][r] = 0.f;

    stage(kt0, cur);
    vm_drain();
    __syncthreads();
    for (int kt = kt0; kt < kt1; ++kt) {
      if (kt + 1 < kt1) stage(kt + 1, cur ^ 1);
      const u16* Kl = &lds[cur][0];
      const u16* Vl = &lds[cur][8192];
      const bool domask = (kt >= ntp - 2);

#pragma unroll
      for (int ts = 0; ts < 2; ++ts) {
        f32x16 stv;
#pragma unroll
        for (int r = 0; r < 16; ++r) stv[r] = 0.f;
        {
          const int row = ts * 32 + l31;
          const int rb = row * 256, sw = ((row ^ (row >> 3)) & 15) << 4;
#pragma unroll
          for (int c = 0; c < 8; ++c) {
            short8 kf = *(const short8*)((const char*)Kl + rb + ((c * 32 + hi * 16) ^ sw));
            stv = __builtin_amdgcn_mfma_f32_32x32x16_bf16(kf, qf[c], stv, 0, 0, 0);
          }
        }

        float pvv[16];
        float mx = -1e30f;
#pragma unroll
        for (int r = 0; r < 16; ++r) {
          float x = stv[r] * KSC;
          if (domask) {
            int kv = kt * 64 + ts * 32 + (r & 3) + 8 * (r >> 2) + 4 * hi;
            if (kv > qrow) x = -1e30f;
          }
          pvv[r] = x;
          mx = fmaxf(mx, x);
        }
        mx = fmaxf(mx, __shfl_xor(mx, 32, 64));

        if (__any(mx > m_run + 8.0f)) {
          float mnew = fmaxf(m_run, mx);
          float corr = exp2_fast(m_run - mnew);
          l_run *= corr;
          m_run = mnew;
#pragma unroll
          for (int r = 0; r < 16; ++r) {
            float cr = __shfl(corr, (r & 3) + 8 * (r >> 2) + 4 * hi, 64);
#pragma unroll
            for (int n = 0; n < 4; ++n) oacc[n][r] *= cr;
          }
        }

        float ls = 0.f;
#pragma unroll
        for (int r = 0; r < 16; ++r) {
          float p = exp2_fast(pvv[r] - m_run);
          pvv[r] = p;
          ls += p;
        }
        l_run += ls + __shfl_xor(ls, 32, 64);

        unsigned W[4][2], Wx[4][2];
#pragma unroll
        for (int g = 0; g < 4; ++g)
#pragma unroll
          for (int i = 0; i < 2; ++i) {
            W[g][i] = cvtpk_bf16(pvv[4 * g + 2 * i], pvv[4 * g + 2 * i + 1]);
            Wx[g][i] = __shfl_xor(W[g][i], 32, 64);
          }

#pragma unroll
        for (int cc = 0; cc < 2; ++cc) {
          short8 paf;
          ((unsigned*)&paf)[0] = hi ? Wx[2 * cc + 1][0] : W[2 * cc][0];
          ((unsigned*)&paf)[1] = hi ? Wx[2 * cc + 1][1] : W[2 * cc][1];
          ((unsigned*)&paf)[2] = hi ? W[2 * cc + 1][0] : Wx[2 * cc][0];
          ((unsigned*)&paf)[3] = hi ? W[2 * cc + 1][1] : Wx[2 * cc][1];
          const int cp = ts * 2 + cc;
#pragma unroll
          for (int n = 0; n < 4; ++n) {
            const int d = n * 32 + l31;
            const int swv = ((d ^ (d >> 3)) & 7) << 4;
            short8 vf = *(const short8*)((const char*)Vl + d * 128 + ((cp * 32 + hi * 16) ^ swv));
            oacc[n] = __builtin_amdgcn_mfma_f32_32x32x16_bf16(paf, vf, oacc[n], 0, 0, 0);
          }
        }
      }
      vm_drain();
      __syncthreads();
      cur ^= 1;
    }

    if (mode == 0) {
#pragma unroll
      for (int r = 0; r < 16; ++r) {
        const int ql = (r & 3) + 8 * (r >> 2) + 4 * hi;
        float lb = __shfl(l_run, ql, 64);
        float inv = 1.0f / lb;
        const int q = q0 + w * 32 + ql;
        u16* op = Ab + ((size_t)(b * S_) + q) * 2048 + hh * 128 + l31;
#pragma unroll
        for (int n = 0; n < 4; ++n) op[n * 32] = f2b(oacc[n][r] * inv);
      }
    } else {
      const int part = mode - 1;
      u16* ob = Op + ((size_t)(part * 256 + pid)) * 128 * 128;
#pragma unroll
      for (int r = 0; r < 16; ++r) {
        const int ql = (r & 3) + 8 * (r >> 2) + 4 * hi;
        const int qq = w * 32 + ql;
#pragma unroll
        for (int n = 0; n < 4; ++n) ob[qq * 128 + n * 32 + l31] = f2b(oacc[n][r]);
      }
      if (hi == 0) {
        float* mlb = Ml + ((size_t)(part * 256 + pid)) * 256;
        mlb[w * 32 + l31] = m_run;
        mlb[128 + w * 32 + l31] = l_run;
      }
    }
  };

  if (half == 0) {
    run_seg(p8, 0, 2 * p8 + 2, 0);
    run_seg(15 - p8, 0, 15 - 2 * p8, 1);
  } else {
    run_seg(15 - p8, 15 - 2 * p8, 32 - 2 * p8, 2);
  }
}

// ---------------- merge split panels ----------------
__global__ __launch_bounds__(256) void attn_combine_kernel(const u16* __restrict__ Op,
                                                           const float* __restrict__ Ml,
                                                           u16* __restrict__ Ab) {
  const int pid = blockIdx.x;  // 0..255
  const int b = pid >> 7, hh = (pid >> 3) & 15, p8 = pid & 7;
  const int pp = 15 - p8;
  const int q = threadIdx.x >> 1;
  const int d0 = (threadIdx.x & 1) * 64;
  const float* ml0 = Ml + (size_t)pid * 256;
  const float* ml1 = Ml + (size_t)(256 + pid) * 256;
  const float m0 = ml0[q], l0 = ml0[128 + q];
  const float m1 = ml1[q], l1 = ml1[128 + q];
  const float m = fmaxf(m0, m1);
  const float w0 = exp2_fast(m0 - m), w1 = exp2_fast(m1 - m);
  const float linv = 1.0f / (w0 * l0 + w1 * l1);
  const u16* o0 = Op + ((size_t)pid * 128 + q) * 128 + d0;
  const u16* o1 = Op + ((size_t)(256 + pid) * 128 + q) * 128 + d0;
  u16* ab = Ab + ((size_t)(b * S_) + pp * 128 + q) * 2048 + hh * 128 + d0;
#pragma unroll
  for (int c = 0; c < 8; ++c) {
    short8 a = *(const short8*)(o0 + c * 8);
    short8 bb = *(const short8*)(o1 + c * 8);
    short8 o;
#pragma unroll
    for (int j = 0; j < 8; ++j)
      o[j] = (short)f2b((w0 * b2f((u16)a[j]) + w1 * b2f((u16)bb[j])) * linv);
    *(short8*)(ab + c * 8) = o;
  }
}

extern "C" void kernel_launch(void* const* d_in, const int* in_sizes, int n_in,
                              void* d_out, int out_size, void* d_ws, size_t ws_size,
                              hipStream_t stream) {
  const float* hs  = (const float*)d_in[0];
  const int*   pid = (const int*)d_in[1];
  const float* Wq  = (const float*)d_in[2];
  const float* Wk  = (const float*)d_in[3];
  const float* Wv  = (const float*)d_in[4];
  const float* Wo  = (const float*)d_in[5];
  const float* qnw = (const float*)d_in[6];
  const float* knw = (const float*)d_in[7];

  float* out0 = (float*)d_out;
  float* kout = out0 + (size_t)B_ * HKV_ * S_ * D_;
  float* vout = kout + (size_t)B_ * HKV_ * S_ * D_;

  char* ws = (char*)d_ws;
  size_t off = 0;
  auto alloc = [&](size_t bytes) {
    void* p = ws + off;
    off += (bytes + 255) & ~(size_t)255;
    return p;
  };
  u16*   Xb    = (u16*)alloc((size_t)4096 * 1024 * 2);
  u16*   Wqkvt = (u16*)alloc((size_t)4096 * 1024 * 2);  // rows: Q 0..2047 (perm), K 2048..3071 (perm), V 3072..4095 (plain)
  u16*   Wot   = (u16*)alloc((size_t)1024 * 2048 * 2);
  float* ct_t  = (float*)alloc((size_t)64 * 2048 * 4);  // [f][s]
  float* st_t  = (float*)alloc((size_t)64 * 2048 * 4);
  u16*   Qbb   = (u16*)alloc((size_t)B_ * H_ * S_ * D_ * 2);
  u16*   Kbb   = (u16*)alloc((size_t)B_ * HKV_ * S_ * D_ * 2);
  u16*   VTb   = (u16*)alloc((size_t)B_ * HKV_ * D_ * S_ * 2);
  u16*   Ab    = (u16*)alloc((size_t)B_ * S_ * H_ * D_ * 2);
  u16*   Op    = (u16*)alloc((size_t)2 * 256 * 128 * 128 * 2);
  float* Ml    = (float*)alloc((size_t)2 * 256 * 256 * 4);

  conv_bf16_kernel<<<4096, 256, 0, stream>>>(hs, Xb, 4096 * 1024 / 4);
  transpose_bf16_kernel<true><<<(2048 / 32) * (1024 / 32), 256, 0, stream>>>(Wq, Wqkvt, 1024, 2048);
  transpose_bf16_kernel<true><<<(1024 / 32) * (1024 / 32), 256, 0, stream>>>(Wk, Wqkvt + (size_t)2048 * 1024, 1024, 1024);
  transpose_bf16_kernel<false><<<(1024 / 32) * (1024 / 32), 256, 0, stream>>>(Wv, Wqkvt + (size_t)3072 * 1024, 1024, 1024);
  transpose_bf16_kernel<false><<<(1024 / 32) * (2048 / 32), 256, 0, stream>>>(Wo, Wot, 2048, 1024);
  rope_table_kernel<<<512, 256, 0, stream>>>(pid, ct_t, st_t);

  // fused QKV projection + norm + rope + layout: 1024 blocks (4/CU)
  gemm_qkv_fused<<<1024, 256, 0, stream>>>(Xb, Wqkvt, qnw, knw, ct_t, st_t,
                                           Qbb, Kbb, kout, vout, VTb);

  attn_kernel<<<512, 256, 0, stream>>>(Qbb, Kbb, VTb, Ab, Op, Ml);
  attn_combine_kernel<<<256, 256, 0, stream>>>(Op, Ml, Ab);

  // O projection: BM=64 tiles -> 512 blocks (2/CU)
  gemm_bt<4096, 1024, 2048, 64><<<8 * 64, 256, 0, stream>>>(Ab, Wot, out0);
}